// Round 6
// baseline (4236.381 us; speedup 1.0000x reference)
//
#include <hip/hip_runtime.h>
#include <hip/hip_bf16.h>
#include <math.h>

// ---------------------------------------------------------------------------
// RAFT-small forward — round 6: HWC + fused im2col split-bf16 MFMA GEMM.
// - All conv inputs live as [HW][Cpad] fp32. k-order = (tap, ci) so a lane's
//   8-elem A-frag = 2 contiguous float4 loads; frags built in-register
//   (hi/lo bf16 split, 3-term MFMA). No A materialization, no pack kernels.
// - corr_lookup: 4 waves/block, shfl-based lattice reduce, HWC output.
// - hx[248]=[net|inp|mot|flow|pad], cmin[128]=[cor|flo2] composed in-place
//   by GEMM epilogues (ooff) + tiny fill kernels. GRU/flow-head fused.
// ---------------------------------------------------------------------------

typedef __attribute__((ext_vector_type(8))) short short8;
typedef __attribute__((ext_vector_type(4))) float f32x4;

static inline int nblk(int n, int b){ return (n + b - 1) / b; }

__device__ __forceinline__ short bf16bits(float v){
  __hip_bfloat16 h = __float2bfloat16(v);
  return *reinterpret_cast<short*>(&h);
}
__device__ __forceinline__ float bf2f(short s){
  unsigned u = ((unsigned)(unsigned short)s) << 16;
  return *reinterpret_cast<float*>(&u);
}

// ---- small utility kernels -------------------------------------------------
__global__ void k_trans_act(const float* __restrict__ in, float* __restrict__ out,
                            int ostride, int ooff, int C, int HW, int act){
  int i = blockIdx.x*256 + threadIdx.x;
  if (i >= C*HW) return;
  int p = i / C, c = i - p*C;
  float v = in[(size_t)c*HW + p];
  v = (act == 1) ? fmaxf(v, 0.f) : tanhf(v);
  out[(size_t)p*ostride + ooff + c] = v;
}
__global__ void k_zero_cols(float* __restrict__ out, int ostride, int c0, int n, int HW){
  int i = blockIdx.x*256 + threadIdx.x;
  if (i >= n*HW) return;
  int p = i / n, c = i - p*n;
  out[(size_t)p*ostride + c0 + c] = 0.f;
}
__global__ void k_init_coords(float* __restrict__ c, int H, int W){
  int p = blockIdx.x*256 + threadIdx.x;
  int HW = H*W;
  if (p < HW){ c[p] = (float)(p % W); c[HW + p] = (float)(p / W); }
}
__global__ void k_transpose_hwc(const float* __restrict__ in, float* __restrict__ out, int HW){
  int i = blockIdx.x*256 + threadIdx.x;
  if (i < HW*128){ int p = i >> 7, c = i & 127; out[i] = in[c*HW + p]; }
}
__global__ void k_pool_hwc(const float* __restrict__ in, float* __restrict__ out, int H2, int W2){
  int i = blockIdx.x*256 + threadIdx.x;
  int n = H2*W2*128;
  if (i >= n) return;
  int c = i & 127, p = i >> 7;
  int ox = p % W2, oy = p / W2;
  int W = 2*W2;
  const float* b = in + ((size_t)(2*oy)*W + 2*ox)*128 + c;
  out[i] = 0.25f*(b[0] + b[128] + b[(size_t)W*128] + b[(size_t)W*128 + 128]);
}
__global__ void k_cat2(const float* __restrict__ a, const float* __restrict__ b,
                       float* __restrict__ o, int n){
  int i = blockIdx.x*256 + threadIdx.x;
  if (i < 2*n) o[i] = (i < n) ? a[i] : b[i-n];
}
// hx cols 0..95 = netc; 240,241 = flow(coords-grid)
__global__ void k_hx_netflow(float* __restrict__ hx, const float* __restrict__ netc,
                             const float* __restrict__ co, int H, int W){
  int HW = H*W;
  int i = blockIdx.x*256 + threadIdx.x;
  if (i >= 98*HW) return;
  int p = i / 98, c = i - p*98;
  float v;
  int oc;
  if (c < 96){ v = netc[(size_t)p*96 + c]; oc = c; }
  else if (c == 96){ v = co[p] - (float)(p % W); oc = 240; }
  else { v = co[HW + p] - (float)(p / W); oc = 241; }
  hx[(size_t)p*248 + oc] = v;
}
// hx cols 0..95 = r*netc  (r = zrb cols 96..191)
__global__ void k_rnet(float* __restrict__ hx, const float* __restrict__ zrb,
                       const float* __restrict__ netc, int HW){
  int i = blockIdx.x*256 + threadIdx.x;
  if (i >= 96*HW) return;
  int p = i / 96, c = i - p*96;
  hx[(size_t)p*248 + c] = zrb[(size_t)p*192 + 96 + c] * netc[(size_t)p*96 + c];
}
// f1 im2row: [HW][104]: ch 2t+j = flow_j at tap t (7x7, zero-pad); cols 98..103 = 0
__global__ void k_f1row(const float* __restrict__ co, float* __restrict__ out, int H, int W){
  int HW = H*W;
  int i = blockIdx.x*256 + threadIdx.x;
  if (i >= HW*49) return;
  int p = i / 49, t = i - p*49;
  int x = p % W, y = p / W;
  int kx = t % 7, ky = t / 7;
  int xx = x + kx - 3, yy = y + ky - 3;
  float v0 = 0.f, v1 = 0.f;
  if ((unsigned)xx < (unsigned)W && (unsigned)yy < (unsigned)H){
    int pp = yy*W + xx;
    v0 = co[pp]      - (float)xx;
    v1 = co[HW + pp] - (float)yy;
  }
  out[(size_t)p*104 + 2*t]     = v0;
  out[(size_t)p*104 + 2*t + 1] = v1;
  if (t == 48){
    #pragma unroll
    for (int c = 98; c < 104; c++) out[(size_t)p*104 + c] = 0.f;
  }
}

// ---- corr lookup: 4 waves/block, shfl lattice reduce, HWC out [HW][200] ----
__global__ __launch_bounds__(256)
void k_corr4(const float* __restrict__ f1h,
             const float* __restrict__ l0, const float* __restrict__ l1,
             const float* __restrict__ l2, const float* __restrict__ l3,
             const float* __restrict__ coords,
             float* __restrict__ out, int H, int W)
{
  int HW = H*W;
  int wv = threadIdx.x >> 6, lane = threadIdx.x & 63;
  int q = blockIdx.x*4 + wv;
  __shared__ __align__(16) float sf1[4][128];
  sf1[wv][lane]      = f1h[(size_t)q*128 + lane];
  sf1[wv][64 + lane] = f1h[(size_t)q*128 + 64 + lane];
  __syncthreads();
  float x = coords[q], y = coords[HW + q];
  const float* const lv[4] = {l0, l1, l2, l3};
  int u = lane & 7, v = lane >> 3;
  int t = lane;
  int j = min(t / 7, 6), k = min(t % 7, 6);
  const float4* a = (const float4*)&sf1[wv][0];
  #pragma unroll
  for (int i = 0; i < 4; i++){
    int Wi = W >> i, Hi = H >> i;
    float sc = 1.0f / (float)(1 << i);
    float xs = x*sc, ys = y*sc;
    float fx = floorf(xs), fy = floorf(ys);
    float wx = xs - fx, wy = ys - fy;
    float xf = fx + (float)(u - 3);
    float yf = fy + (float)(v - 3);
    float d = 0.0f;
    if (xf >= 0.0f && xf <= (float)(Wi-1) && yf >= 0.0f && yf <= (float)(Hi-1)){
      const float4* b = (const float4*)(lv[i] + ((size_t)((int)yf)*Wi + (int)xf)*128);
      float acc = 0.0f;
      #pragma unroll
      for (int kk = 0; kk < 32; kk++){
        float4 av = a[kk], bv = b[kk];
        acc += av.x*bv.x + av.y*bv.y + av.z*bv.z + av.w*bv.w;
      }
      d = acc;
    }
    float d00 = __shfl(d,  k   *8 + j);
    float d10 = __shfl(d,  k   *8 + j + 1);
    float d01 = __shfl(d, (k+1)*8 + j);
    float d11 = __shfl(d, (k+1)*8 + j + 1);
    if (t < 49){
      float val = (1.f-wx)*(1.f-wy)*d00 + wx*(1.f-wy)*d10
                + (1.f-wx)*wy*d01 + wx*wy*d11;
      out[(size_t)q*200 + i*49 + t] = val * 0.08838834764831845f;
    }
  }
  if (lane >= 49 && lane < 53) out[(size_t)q*200 + 147 + lane] = 0.f;
}

__global__ void k_upflow(const float* __restrict__ cin, float* __restrict__ outp,
                         int Hin, int Win, int Hout, int Wout, float n, int subtract)
{
  int idx = blockIdx.x*256 + threadIdx.x;
  int HWo = Hout*Wout;
  if (idx >= 2*HWo) return;
  int c = idx / HWo;
  int rem = idx - c*HWo;
  int py = rem / Wout, px = rem % Wout;
  float posy = (float)py * (float)(Hin-1) / (float)(Hout-1);
  float posx = (float)px * (float)(Win-1) / (float)(Wout-1);
  int iy = (int)floorf(posy); iy = max(0, min(iy, Hin-2));
  int ix = (int)floorf(posx); ix = max(0, min(ix, Win-2));
  float wy = posy - (float)iy, wx = posx - (float)ix;
  const float* base = cin + (size_t)c*Hin*Win;
  float s00 = 0.f, s10 = 0.f, s01 = 0.f, s11 = 0.f;
  if (subtract){
    if (c == 0){ s00 = (float)ix; s01 = (float)ix; s10 = (float)(ix+1); s11 = (float)(ix+1); }
    else       { s00 = (float)iy; s10 = (float)iy; s01 = (float)(iy+1); s11 = (float)(iy+1); }
  }
  float v00 = base[(size_t)iy*Win + ix]       - s00;
  float v10 = base[(size_t)iy*Win + ix + 1]   - s10;
  float v01 = base[(size_t)(iy+1)*Win + ix]   - s01;
  float v11 = base[(size_t)(iy+1)*Win + ix+1] - s11;
  float val = (1.f-wy)*((1.f-wx)*v00 + wx*v10) + wy*((1.f-wx)*v01 + wx*v11);
  outp[idx] = n * val;
}

// ---- pack-B: weights -> frag order, k = tap*Cpad + ci, hi/lo split --------
// mode 0: v = w[col][ci][tap] ([Cout][Cin][KT]); zr col-split (w0|w1 at `split`)
// mode 1 (f1 im2row): v = w0[col][ci&1][ci>>1]  (KT arg = 1)
__global__ void k_pack_b(const float* __restrict__ w0, const float* __restrict__ w1,
                         int split, int Cout, int Cin, int Cpad, int KT, int mode,
                         short8* __restrict__ out, int nt16, int ktn)
{
  int gid = blockIdx.x*256 + threadIdx.x;
  if (gid >= ktn*nt16*64) return;
  int lane = gid & 63, blk = gid >> 6;
  int ct = blk % nt16, kt = blk / nt16;
  int col = ct*16 + (lane & 15);
  int kbase = kt*32 + (lane >> 4)*8;
  short8 ohi, olo;
  #pragma unroll
  for (int e = 0; e < 8; e++){
    int kk = kbase + e;
    int ci = kk % Cpad, tap = kk / Cpad;
    float v = 0.f;
    if (col < Cout && ci < Cin && tap < KT){
      if (mode == 1){
        v = w0[((size_t)col*2 + (ci & 1))*49 + (ci >> 1)];
      } else {
        const float* wp = (col < split) ? (w0 + (size_t)col*Cin*KT)
                                        : (w1 + (size_t)(col - split)*Cin*KT);
        v = wp[(size_t)ci*KT + tap];
      }
    }
    short hi = bf16bits(v);
    ohi[e] = hi;
    olo[e] = bf16bits(v - bf2f(hi));
  }
  out[(size_t)blk*128 + lane]      = ohi;
  out[(size_t)blk*128 + 64 + lane] = olo;
}

// ---- fused im2col split-bf16 GEMM -----------------------------------------
// WG = 4 waves; wave w: rows mt*16..+15, mt = bx*4+w; covers NCT 64-col blocks.
// EPI: 0 store HWC; 1 GRU (HWC); 2 add into CHW target.
template<int KTW, int NCT, int ACT, int EPI>
__global__ __launch_bounds__(256)
void k_cgemm(const float* __restrict__ in, int Cpad, int ktn,
             const short8* __restrict__ B, int nt16,
             const float* __restrict__ bias,
             float* __restrict__ out, int ostride, int ooff, int Cout,
             int H, int W,
             const float* __restrict__ ez, int ezs,
             const float* __restrict__ eold, int eos)
{
  const int KT = KTW*KTW, P = KTW/2;
  int HW = H*W;
  int lane = threadIdx.x & 63;
  int mt = blockIdx.x*4 + (threadIdx.x >> 6);
  int p = mt*16 + (lane & 15);
  int x = p % W, y = p / W;
  int kq = (lane >> 4)*8;

  f32x4 acc[NCT][4];
  #pragma unroll
  for (int cb = 0; cb < NCT; cb++)
    #pragma unroll
    for (int f = 0; f < 4; f++) acc[cb][f] = f32x4{0.f,0.f,0.f,0.f};

  int ci = kq, tap = 0;
  for (int kt = 0; kt < ktn; kt++){
    int dy = tap / KTW - P, dx = tap % KTW - P;
    int xx = x + dx, yy = y + dy;
    bool ok = (tap < KT) && ((unsigned)xx < (unsigned)W) && ((unsigned)yy < (unsigned)H);
    float4 va = make_float4(0.f,0.f,0.f,0.f), vb = va;
    if (ok){
      const float4* ip = (const float4*)(in + (size_t)(yy*W + xx)*Cpad + ci);
      va = ip[0]; vb = ip[1];
    }
    short8 ah, al;
    {
      float vv[8] = {va.x,va.y,va.z,va.w,vb.x,vb.y,vb.z,vb.w};
      #pragma unroll
      for (int e = 0; e < 8; e++){
        short hi = bf16bits(vv[e]);
        ah[e] = hi;
        al[e] = bf16bits(vv[e] - bf2f(hi));
      }
    }
    const short8* bk = B + (size_t)kt*nt16*128 + lane;
    #pragma unroll
    for (int cb = 0; cb < NCT; cb++){
      #pragma unroll
      for (int f = 0; f < 4; f++){
        const short8* bp = bk + (size_t)(cb*4 + f)*128;
        short8 bh = bp[0], bl = bp[64];
        acc[cb][f] = __builtin_amdgcn_mfma_f32_16x16x32_bf16(ah, bh, acc[cb][f], 0, 0, 0);
        acc[cb][f] = __builtin_amdgcn_mfma_f32_16x16x32_bf16(al, bh, acc[cb][f], 0, 0, 0);
        acc[cb][f] = __builtin_amdgcn_mfma_f32_16x16x32_bf16(ah, bl, acc[cb][f], 0, 0, 0);
      }
    }
    ci += 32;
    if (ci >= Cpad){ ci -= Cpad; tap++; }
  }

  int rowb = mt*16 + ((lane >> 4) << 2);
  int colq = lane & 15;
  #pragma unroll
  for (int cb = 0; cb < NCT; cb++){
    #pragma unroll
    for (int f = 0; f < 4; f++){
      int col = cb*64 + f*16 + colq;
      if (col < Cout){
        float bb = bias[col];
        #pragma unroll
        for (int r = 0; r < 4; r++){
          float val = acc[cb][f][r] + bb;
          if (ACT == 1) val = fmaxf(val, 0.f);
          if (ACT == 2) val = 1.f/(1.f + expf(-val));
          if (ACT == 3) val = tanhf(val);
          int row = rowb + r;
          if constexpr (EPI == 1){
            float zz = ez[(size_t)row*ezs + col];
            out[(size_t)row*ostride + ooff + col] =
                (1.f - zz)*eold[(size_t)row*eos + col] + zz*val;
          } else if constexpr (EPI == 2){
            out[(size_t)col*HW + row] += val;
          } else {
            out[(size_t)row*ostride + ooff + col] = val;
          }
        }
      }
    }
  }
}

extern "C" void kernel_launch(void* const* d_in, const int* in_sizes, int n_in,
                              void* d_out, int out_size, void* d_ws, size_t ws_size,
                              hipStream_t stream)
{
  (void)in_sizes; (void)n_in; (void)out_size; (void)ws_size;
  const float* f1s[3]    = {(const float*)d_in[0], (const float*)d_in[2], (const float*)d_in[4]};
  const float* f2s[3]    = {(const float*)d_in[1], (const float*)d_in[3], (const float*)d_in[5]};
  const float* net_in[3] = {(const float*)d_in[6], (const float*)d_in[8], (const float*)d_in[10]};
  const float* inp_in[3] = {(const float*)d_in[7], (const float*)d_in[9], (const float*)d_in[11]};
  const float* Wc1 = (const float*)d_in[12]; const float* bc1 = (const float*)d_in[13];
  const float* Wf1 = (const float*)d_in[14]; const float* bf1 = (const float*)d_in[15];
  const float* Wf2 = (const float*)d_in[16]; const float* bf2 = (const float*)d_in[17];
  const float* Wm  = (const float*)d_in[18]; const float* bm  = (const float*)d_in[19];
  const float* Wz  = (const float*)d_in[20]; const float* bz  = (const float*)d_in[21];
  const float* Wr  = (const float*)d_in[22]; const float* br  = (const float*)d_in[23];
  const float* Wq  = (const float*)d_in[24]; const float* bq  = (const float*)d_in[25];
  const float* Wh1 = (const float*)d_in[26]; const float* bh1 = (const float*)d_in[27];
  const float* Wh2 = (const float*)d_in[28]; const float* bh2 = (const float*)d_in[29];

  const int Hs[3] = {96, 48, 24};

  float* ws = (float*)d_ws;
  size_t off = 0;
  auto alloc = [&](size_t nfl)->float*{
    float* p = ws + off;
    off += (nfl + 3) & ~((size_t)3);
    return p;
  };

  float* f2l[3][4]; float* f1h[3]; float* netP[3][2]; float* hxb[3]; float* coords[3];
  for (int si = 0; si < 3; si++){
    int H = Hs[si], HW = H*H;
    for (int l = 0; l < 4; l++) f2l[si][l] = alloc((size_t)(HW >> (2*l))*128);
    f1h[si]     = alloc((size_t)HW*128);
    netP[si][0] = alloc((size_t)HW*96);
    netP[si][1] = alloc((size_t)HW*96);
    hxb[si]     = alloc((size_t)HW*248);
    coords[si]  = alloc((size_t)2*HW);
  }
  const int HWm = 96*96;
  float* corrfeat = alloc((size_t)HWm*200);
  float* f1row    = alloc((size_t)HWm*104);
  float* flo1     = alloc((size_t)HWm*64);
  float* cmin     = alloc((size_t)HWm*128);
  float* zrb      = alloc((size_t)HWm*192);
  float* t128     = alloc((size_t)HWm*128);
  // B packs: ktn*nt16 blocks of 512 floats (128 short8 hi|lo)
  float* Bc1 = alloc((size_t)7*8*512);
  float* Bf1 = alloc((size_t)4*4*512);
  float* Bf2 = alloc((size_t)18*4*512);
  float* Bm  = alloc((size_t)36*8*512);
  float* Bzr = alloc((size_t)70*12*512);
  float* Bq  = alloc((size_t)70*8*512);
  float* Bh1 = alloc((size_t)27*8*512);
  float* Bh2 = alloc((size_t)36*4*512);
  float* bzr = alloc(192);

  #define NB(n) dim3((unsigned)nblk((n), 256))

  // ---- one-time B packs ----
  k_pack_b<<<NB(7*8*64),  256, 0, stream>>>(Wc1, Wc1, 96, 96, 196, 200, 1, 0, (short8*)Bc1, 8, 7);
  k_pack_b<<<NB(4*4*64),  256, 0, stream>>>(Wf1, Wf1, 64, 64, 98, 104, 1, 1, (short8*)Bf1, 4, 4);
  k_pack_b<<<NB(18*4*64), 256, 0, stream>>>(Wf2, Wf2, 32, 32, 64, 64, 9, 0, (short8*)Bf2, 4, 18);
  k_pack_b<<<NB(36*8*64), 256, 0, stream>>>(Wm, Wm, 80, 80, 128, 128, 9, 0, (short8*)Bm, 8, 36);
  k_pack_b<<<NB(70*12*64),256, 0, stream>>>(Wz, Wr, 96, 192, 242, 248, 9, 0, (short8*)Bzr, 12, 70);
  k_pack_b<<<NB(70*8*64), 256, 0, stream>>>(Wq, Wq, 96, 96, 242, 248, 9, 0, (short8*)Bq, 8, 70);
  k_pack_b<<<NB(27*8*64), 256, 0, stream>>>(Wh1, Wh1, 128, 128, 96, 96, 9, 0, (short8*)Bh1, 8, 27);
  k_pack_b<<<NB(36*4*64), 256, 0, stream>>>(Wh2, Wh2, 2, 2, 128, 128, 9, 0, (short8*)Bh2, 4, 36);
  k_cat2<<<dim3(1), 256, 0, stream>>>(bz, br, bzr, 96);

  // ---- per-scale init ----
  for (int si = 0; si < 3; si++){
    int H = Hs[si], HW = H*H;
    k_trans_act<<<NB(96*HW), 256, 0, stream>>>(net_in[si], netP[si][0], 96, 0, 96, HW, 0);
    k_trans_act<<<NB(64*HW), 256, 0, stream>>>(inp_in[si], hxb[si], 248, 96, 64, HW, 1);
    k_zero_cols<<<NB(6*HW), 256, 0, stream>>>(hxb[si], 248, 242, 6, HW);
    k_init_coords<<<NB(HW), 256, 0, stream>>>(coords[si], H, H);
    k_transpose_hwc<<<NB(HW*128), 256, 0, stream>>>(f2s[si], f2l[si][0], HW);
    k_transpose_hwc<<<NB(HW*128), 256, 0, stream>>>(f1s[si], f1h[si], HW);
    for (int l = 1; l < 4; l++){
      int Hl = H >> l;
      k_pool_hwc<<<NB(Hl*Hl*128), 256, 0, stream>>>(f2l[si][l-1], f2l[si][l], Hl, Hl);
    }
  }

  int cur[3] = {0, 0, 0};
  const int seq[6] = {2, 2, 1, 1, 0, 0};
  for (int it = 0; it < 6; it++){
    int si = seq[it];
    int H = Hs[si], W = H, HW = H*W;
    int MT = HW/16;
    float s = (si == 0) ? 2.0f : ((si == 1) ? 4.0f : 8.0f);
    float* netc = netP[si][cur[si]];
    float* netn = netP[si][cur[si]^1];
    float* co   = coords[si];
    float* hx   = hxb[si];
    unsigned gx = (unsigned)(MT/4);

    k_corr4<<<dim3((unsigned)(HW/4)), 256, 0, stream>>>(
        f1h[si], f2l[si][0], f2l[si][1], f2l[si][2], f2l[si][3], co, corrfeat, H, W);
    k_hx_netflow<<<NB(98*HW), 256, 0, stream>>>(hx, netc, co, H, W);
    k_f1row<<<NB(49*HW), 256, 0, stream>>>(co, f1row, H, W);

    // c1: corr[200] -> cmin cols 0..95 (relu)
    k_cgemm<1,2,1,0><<<dim3(gx), 256, 0, stream>>>(corrfeat, 200, 7, (short8*)Bc1, 8, bc1,
        cmin, 128, 0, 96, H, W, nullptr, 0, nullptr, 0);
    // f1: f1row[104] -> flo1[64] (relu)
    k_cgemm<1,1,1,0><<<dim3(gx), 256, 0, stream>>>(f1row, 104, 4, (short8*)Bf1, 4, bf1,
        flo1, 64, 0, 64, H, W, nullptr, 0, nullptr, 0);
    // f2: flo1 -> cmin cols 96..127 (relu)
    k_cgemm<3,1,1,0><<<dim3(gx), 256, 0, stream>>>(flo1, 64, 18, (short8*)Bf2, 4, bf2,
        cmin, 128, 96, 32, H, W, nullptr, 0, nullptr, 0);
    // m: cmin[128] -> hx cols 160..239 (relu)
    k_cgemm<3,2,1,0><<<dim3(gx), 256, 0, stream>>>(cmin, 128, 36, (short8*)Bm, 8, bm,
        hx, 248, 160, 80, H, W, nullptr, 0, nullptr, 0);
    // zr: hx[248] -> zrb[192] (sigmoid)
    k_cgemm<3,3,2,0><<<dim3(gx), 256, 0, stream>>>(hx, 248, 70, (short8*)Bzr, 12, bzr,
        zrb, 192, 0, 192, H, W, nullptr, 0, nullptr, 0);
    // r*net into hx cols 0..95
    k_rnet<<<NB(96*HW), 256, 0, stream>>>(hx, zrb, netc, HW);
    // q: hx -> netn (tanh + GRU epilogue; z = zrb cols 0..95)
    k_cgemm<3,2,3,1><<<dim3(gx), 256, 0, stream>>>(hx, 248, 70, (short8*)Bq, 8, bq,
        netn, 96, 0, 96, H, W, zrb, 192, netc, 96);
    // fh1: netn[96] -> t128[128] (relu)
    k_cgemm<3,2,1,0><<<dim3(gx), 256, 0, stream>>>(netn, 96, 27, (short8*)Bh1, 8, bh1,
        t128, 128, 0, 128, H, W, nullptr, 0, nullptr, 0);
    // fh2: t128 -> coords (CHW +=)
    k_cgemm<3,1,0,2><<<dim3(gx), 256, 0, stream>>>(t128, 128, 36, (short8*)Bh2, 4, bh2,
        co, 0, 0, 2, H, W, nullptr, 0, nullptr, 0);

    // prediction + coarse-to-fine handoff
    k_upflow<<<NB(2*192*192), 256, 0, stream>>>(co, (float*)d_out + (size_t)it*2*192*192,
                                                H, W, 192, 192, s, 1);
    if (si > 0){
      int Hf = Hs[si-1];
      k_upflow<<<NB(2*Hf*Hf), 256, 0, stream>>>(co, coords[si-1], H, W, Hf, Hf, 2.0f, 0);
    }
    cur[si] ^= 1;
  }
  #undef NB
}

// Round 7
// 1598.645 us; speedup vs baseline: 2.6500x; 2.6500x over previous
//
#include <hip/hip_runtime.h>
#include <hip/hip_bf16.h>
#include <math.h>

// ---------------------------------------------------------------------------
// RAFT-small forward — round 7: hybrid r5+r6.
// HWC buffers everywhere; pack-A (coalesced, fragment-order, hi/lo split-bf16)
// + GEMM on (M-tiles x N-tiles) grid (r5 parallelism). k-order = tap*Cpad+ci
// with Cpad multiple of 32; q reuses zr's A for shared chunks (per-kt select).
// corr lookup writes HWC (r6 fix). 3-term split-bf16 MFMA, fp32 accum.
// ---------------------------------------------------------------------------

typedef __attribute__((ext_vector_type(8))) short short8;
typedef __attribute__((ext_vector_type(4))) float f32x4;

static inline int nblk(int n, int b){ return (n + b - 1) / b; }

__device__ __forceinline__ short bf16bits(float v){
  __hip_bfloat16 h = __float2bfloat16(v);
  return *reinterpret_cast<short*>(&h);
}
__device__ __forceinline__ float bf2f(short s){
  unsigned u = ((unsigned)(unsigned short)s) << 16;
  return *reinterpret_cast<float*>(&u);
}

// ---- utility kernels -------------------------------------------------------
__global__ void k_trans_act(const float* __restrict__ in, float* __restrict__ out,
                            int ostride, int ooff, int C, int HW, int act){
  int i = blockIdx.x*256 + threadIdx.x;
  if (i >= C*HW) return;
  int p = i / C, c = i - p*C;
  float v = in[(size_t)c*HW + p];
  v = (act == 1) ? fmaxf(v, 0.f) : tanhf(v);
  out[(size_t)p*ostride + ooff + c] = v;
}
__global__ void k_zero_cols(float* __restrict__ out, int ostride, int c0, int n, int HW){
  int i = blockIdx.x*256 + threadIdx.x;
  if (i >= n*HW) return;
  int p = i / n, c = i - p*n;
  out[(size_t)p*ostride + c0 + c] = 0.f;
}
__global__ void k_init_coords(float* __restrict__ c, int H, int W){
  int p = blockIdx.x*256 + threadIdx.x;
  int HW = H*W;
  if (p < HW){ c[p] = (float)(p % W); c[HW + p] = (float)(p / W); }
}
__global__ void k_transpose_hwc(const float* __restrict__ in, float* __restrict__ out, int HW){
  int i = blockIdx.x*256 + threadIdx.x;
  if (i < HW*128){ int p = i >> 7, c = i & 127; out[i] = in[c*HW + p]; }
}
__global__ void k_pool_hwc(const float* __restrict__ in, float* __restrict__ out, int H2, int W2){
  int i = blockIdx.x*256 + threadIdx.x;
  int n = H2*W2*128;
  if (i >= n) return;
  int c = i & 127, p = i >> 7;
  int ox = p % W2, oy = p / W2;
  int W = 2*W2;
  const float* b = in + ((size_t)(2*oy)*W + 2*ox)*128 + c;
  out[i] = 0.25f*(b[0] + b[128] + b[(size_t)W*128] + b[(size_t)W*128 + 128]);
}
__global__ void k_cat2(const float* __restrict__ a, const float* __restrict__ b,
                       float* __restrict__ o, int n){
  int i = blockIdx.x*256 + threadIdx.x;
  if (i < 2*n) o[i] = (i < n) ? a[i] : b[i-n];
}
// hx (stride 256): cols 0..95 = netc; 240,241 = flow(coords - grid)
__global__ void k_hx_netflow(float* __restrict__ hx, const float* __restrict__ netc,
                             const float* __restrict__ co, int H, int W){
  int HW = H*W;
  int i = blockIdx.x*256 + threadIdx.x;
  if (i >= 98*HW) return;
  int p = i / 98, c = i - p*98;
  float v; int oc;
  if (c < 96){ v = netc[(size_t)p*96 + c]; oc = c; }
  else if (c == 96){ v = co[p] - (float)(p % W); oc = 240; }
  else { v = co[HW + p] - (float)(p / W); oc = 241; }
  hx[(size_t)p*256 + oc] = v;
}

// ---- corr lookup: 4 waves/block, shfl lattice reduce, HWC out [HW][224] ----
__global__ __launch_bounds__(256)
void k_corr4(const float* __restrict__ f1h,
             const float* __restrict__ l0, const float* __restrict__ l1,
             const float* __restrict__ l2, const float* __restrict__ l3,
             const float* __restrict__ coords,
             float* __restrict__ out, int H, int W)
{
  int HW = H*W;
  int wv = threadIdx.x >> 6, lane = threadIdx.x & 63;
  int q = blockIdx.x*4 + wv;
  __shared__ __align__(16) float sf1[4][128];
  sf1[wv][lane]      = f1h[(size_t)q*128 + lane];
  sf1[wv][64 + lane] = f1h[(size_t)q*128 + 64 + lane];
  __syncthreads();
  float x = coords[q], y = coords[HW + q];
  const float* const lv[4] = {l0, l1, l2, l3};
  int u = lane & 7, v = lane >> 3;
  int t = lane;
  int j = min(t / 7, 6), k = min(t % 7, 6);
  const float4* a = (const float4*)&sf1[wv][0];
  #pragma unroll
  for (int i = 0; i < 4; i++){
    int Wi = W >> i, Hi = H >> i;
    float sc = 1.0f / (float)(1 << i);
    float xs = x*sc, ys = y*sc;
    float fx = floorf(xs), fy = floorf(ys);
    float wx = xs - fx, wy = ys - fy;
    float xf = fx + (float)(u - 3);
    float yf = fy + (float)(v - 3);
    float d = 0.0f;
    if (xf >= 0.0f && xf <= (float)(Wi-1) && yf >= 0.0f && yf <= (float)(Hi-1)){
      const float4* b = (const float4*)(lv[i] + ((size_t)((int)yf)*Wi + (int)xf)*128);
      float acc = 0.0f;
      #pragma unroll
      for (int kk = 0; kk < 32; kk++){
        float4 av = a[kk], bv = b[kk];
        acc += av.x*bv.x + av.y*bv.y + av.z*bv.z + av.w*bv.w;
      }
      d = acc;
    }
    float d00 = __shfl(d,  k   *8 + j);
    float d10 = __shfl(d,  k   *8 + j + 1);
    float d01 = __shfl(d, (k+1)*8 + j);
    float d11 = __shfl(d, (k+1)*8 + j + 1);
    if (t < 49){
      float val = (1.f-wx)*(1.f-wy)*d00 + wx*(1.f-wy)*d10
                + (1.f-wx)*wy*d01 + wx*wy*d11;
      out[(size_t)q*224 + i*49 + t] = val * 0.08838834764831845f;
    }
  }
  if (lane < 28) out[(size_t)q*224 + 196 + lane] = 0.f;
}

__global__ void k_upflow(const float* __restrict__ cin, float* __restrict__ outp,
                         int Hin, int Win, int Hout, int Wout, float n, int subtract)
{
  int idx = blockIdx.x*256 + threadIdx.x;
  int HWo = Hout*Wout;
  if (idx >= 2*HWo) return;
  int c = idx / HWo;
  int rem = idx - c*HWo;
  int py = rem / Wout, px = rem % Wout;
  float posy = (float)py * (float)(Hin-1) / (float)(Hout-1);
  float posx = (float)px * (float)(Win-1) / (float)(Wout-1);
  int iy = (int)floorf(posy); iy = max(0, min(iy, Hin-2));
  int ix = (int)floorf(posx); ix = max(0, min(ix, Win-2));
  float wy = posy - (float)iy, wx = posx - (float)ix;
  const float* base = cin + (size_t)c*Hin*Win;
  float s00 = 0.f, s10 = 0.f, s01 = 0.f, s11 = 0.f;
  if (subtract){
    if (c == 0){ s00 = (float)ix; s01 = (float)ix; s10 = (float)(ix+1); s11 = (float)(ix+1); }
    else       { s00 = (float)iy; s10 = (float)iy; s01 = (float)(iy+1); s11 = (float)(iy+1); }
  }
  float v00 = base[(size_t)iy*Win + ix]       - s00;
  float v10 = base[(size_t)iy*Win + ix + 1]   - s10;
  float v01 = base[(size_t)(iy+1)*Win + ix]   - s01;
  float v11 = base[(size_t)(iy+1)*Win + ix+1] - s11;
  float val = (1.f-wy)*((1.f-wx)*v00 + wx*v10) + wy*((1.f-wx)*v01 + wx*v11);
  outp[idx] = n * val;
}

// ---------------------------------------------------------------------------
// pack-A: im2col in MFMA A-frag order from HWC input, hi/lo split.
// k = tap*Cpad + ci (Cpad = CH32*32). Lane l of block (mt,kt) holds
// A[mt*16+(l&15)][kt*32+(l>>4)*8+e]. Block = 128 short8: hi@lane, lo@lane+64.
// MODE 0: plain A[pp*sA+oA+ci]. MODE 1: A*Bm (r*net). MODE 2: flow-from-coords
// im2row (ci = 2*tap7 + j over 7x7 taps; KTW ignored).
// ---------------------------------------------------------------------------
template<int KTW, int MODE>
__global__ void k_packa(const float* __restrict__ A, int sA, int oA,
                        const float* __restrict__ Bm, int sB, int oB,
                        short8* __restrict__ out, int H, int W, int CH32, int KTN)
{
  const int P = KTW/2;
  int HW = H*W, MT = HW >> 4;
  int gid = blockIdx.x*256 + threadIdx.x;
  if (gid >= MT*KTN*64) return;
  int lane = gid & 63, blk = gid >> 6;
  int kt = blk % KTN, mt = blk / KTN;
  int p = mt*16 + (lane & 15);
  int x = p % W, y = p / W;
  int tap = kt / CH32, chunk = kt - tap*CH32;
  int ci0 = chunk*32 + (lane >> 4)*8;
  float vv[8];
  if (MODE == 2){
    #pragma unroll
    for (int e = 0; e < 8; e++){
      int ci = ci0 + e;
      float v = 0.f;
      if (ci < 98){
        int t7 = ci >> 1, j = ci & 1;
        int dx = t7 % 7 - 3, dy = t7 / 7 - 3;
        int xx = x + dx, yy = y + dy;
        if ((unsigned)xx < (unsigned)W && (unsigned)yy < (unsigned)H)
          v = A[(size_t)j*HW + yy*W + xx] - (float)(j ? yy : xx);
      }
      vv[e] = v;
    }
  } else {
    int dx = tap % KTW - P, dy = tap / KTW - P;
    int xx = x + dx, yy = y + dy;
    bool ok = ((unsigned)xx < (unsigned)W) && ((unsigned)yy < (unsigned)H);
    if (ok){
      const float4* ap = (const float4*)(A + (size_t)(yy*W + xx)*sA + oA + ci0);
      float4 a0 = ap[0], a1 = ap[1];
      vv[0]=a0.x; vv[1]=a0.y; vv[2]=a0.z; vv[3]=a0.w;
      vv[4]=a1.x; vv[5]=a1.y; vv[6]=a1.z; vv[7]=a1.w;
      if (MODE == 1){
        const float4* bp = (const float4*)(Bm + (size_t)(yy*W + xx)*sB + oB + ci0);
        float4 b0 = bp[0], b1 = bp[1];
        vv[0]*=b0.x; vv[1]*=b0.y; vv[2]*=b0.z; vv[3]*=b0.w;
        vv[4]*=b1.x; vv[5]*=b1.y; vv[6]*=b1.z; vv[7]*=b1.w;
      }
    } else {
      #pragma unroll
      for (int e = 0; e < 8; e++) vv[e] = 0.f;
    }
  }
  short8 hi8, lo8;
  #pragma unroll
  for (int e = 0; e < 8; e++){
    short h = bf16bits(vv[e]);
    hi8[e] = h;
    lo8[e] = bf16bits(vv[e] - bf2f(h));
  }
  out[(size_t)blk*128 + lane]      = hi8;
  out[(size_t)blk*128 + 64 + lane] = lo8;
}

// pack-B: weights -> frag order, k = tap*Cpad+ci, hi/lo split. zr col-split.
// mode 1: f1 im2row weights (v = w0[col][ci&1][ci>>1]).
__global__ void k_packb(const float* __restrict__ w0, const float* __restrict__ w1,
                        int split, int Cout, int Cin, int KT, int CH32, int mode,
                        short8* __restrict__ out, int nt16, int KTN)
{
  int gid = blockIdx.x*256 + threadIdx.x;
  if (gid >= KTN*nt16*64) return;
  int lane = gid & 63, blk = gid >> 6;
  int ct = blk % nt16, kt = blk / nt16;
  int col = ct*16 + (lane & 15);
  int tap = kt / CH32, chunk = kt - tap*CH32;
  int ci0 = chunk*32 + (lane >> 4)*8;
  short8 hi8, lo8;
  #pragma unroll
  for (int e = 0; e < 8; e++){
    int ci = ci0 + e;
    float v = 0.f;
    if (col < Cout && ci < Cin && tap < KT){
      if (mode == 1){
        v = w0[((size_t)col*2 + (ci & 1))*49 + (ci >> 1)];
      } else {
        const float* wp = (col < split) ? (w0 + (size_t)col*Cin*KT)
                                        : (w1 + (size_t)(col - split)*Cin*KT);
        v = wp[(size_t)ci*KT + tap];
      }
    }
    short h = bf16bits(v);
    hi8[e] = h;
    lo8[e] = bf16bits(v - bf2f(h));
  }
  out[(size_t)blk*128 + lane]      = hi8;
  out[(size_t)blk*128 + 64 + lane] = lo8;
}

// ---------------------------------------------------------------------------
// GEMM: wave = 16 rows x 64 cols, WG = 4 waves. grid (MT/4, nt16/4).
// NQ>0: chunks c<NQ of each tap read from A0 (q's r*net replacement).
// EPI: 0 store HWC; 1 GRU; 2 add into CHW.
// ---------------------------------------------------------------------------
template<int ACT, int EPI, int NQ>
__global__ __launch_bounds__(256)
void k_gemm7(const short8* __restrict__ A1, const short8* __restrict__ A0,
             int KTN, int KTN0, int CH32,
             const short8* __restrict__ B, int nt16, const float* __restrict__ bias,
             float* __restrict__ out, int ostride, int ooff, int Cout, int HW,
             const float* __restrict__ ez, int ezs,
             const float* __restrict__ eold, int eos)
{
  int lane = threadIdx.x & 63;
  int mt = blockIdx.x*4 + (threadIdx.x >> 6);
  int ct0 = blockIdx.y*4;

  f32x4 acc0 = {0.f,0.f,0.f,0.f}, acc1 = acc0, acc2 = acc0, acc3 = acc0;
  const short8* a1p = A1 + (size_t)mt*KTN*128 + lane;
  const short8* a0p = (NQ > 0) ? (A0 + (size_t)mt*KTN0*128 + lane) : nullptr;

  int c = 0, t0 = 0;
  #pragma unroll 2
  for (int kt = 0; kt < KTN; kt++){
    const short8* ap = a1p + (size_t)kt*128;
    if (NQ > 0 && c < NQ) ap = a0p + (size_t)t0*128;
    short8 ah = ap[0], al = ap[64];
    const short8* bp = B + ((size_t)kt*nt16 + ct0)*128 + lane;
    short8 bh0 = bp[0],   bl0 = bp[64];
    short8 bh1 = bp[128], bl1 = bp[192];
    short8 bh2 = bp[256], bl2 = bp[320];
    short8 bh3 = bp[384], bl3 = bp[448];
    acc0 = __builtin_amdgcn_mfma_f32_16x16x32_bf16(ah, bh0, acc0, 0, 0, 0);
    acc1 = __builtin_amdgcn_mfma_f32_16x16x32_bf16(ah, bh1, acc1, 0, 0, 0);
    acc2 = __builtin_amdgcn_mfma_f32_16x16x32_bf16(ah, bh2, acc2, 0, 0, 0);
    acc3 = __builtin_amdgcn_mfma_f32_16x16x32_bf16(ah, bh3, acc3, 0, 0, 0);
    acc0 = __builtin_amdgcn_mfma_f32_16x16x32_bf16(al, bh0, acc0, 0, 0, 0);
    acc1 = __builtin_amdgcn_mfma_f32_16x16x32_bf16(al, bh1, acc1, 0, 0, 0);
    acc2 = __builtin_amdgcn_mfma_f32_16x16x32_bf16(al, bh2, acc2, 0, 0, 0);
    acc3 = __builtin_amdgcn_mfma_f32_16x16x32_bf16(al, bh3, acc3, 0, 0, 0);
    acc0 = __builtin_amdgcn_mfma_f32_16x16x32_bf16(ah, bl0, acc0, 0, 0, 0);
    acc1 = __builtin_amdgcn_mfma_f32_16x16x32_bf16(ah, bl1, acc1, 0, 0, 0);
    acc2 = __builtin_amdgcn_mfma_f32_16x16x32_bf16(ah, bl2, acc2, 0, 0, 0);
    acc3 = __builtin_amdgcn_mfma_f32_16x16x32_bf16(ah, bl3, acc3, 0, 0, 0);
    if (NQ > 0){ if (c < NQ) t0++; if (++c == CH32) c = 0; }
  }

  int rowb = mt*16 + ((lane >> 4) << 2);
  int colq = lane & 15;
  f32x4 av[4] = {acc0, acc1, acc2, acc3};
  #pragma unroll
  for (int f = 0; f < 4; f++){
    int col = (ct0 + f)*16 + colq;
    if (col < Cout){
      float bb = bias[col];
      #pragma unroll
      for (int r = 0; r < 4; r++){
        float val = av[f][r] + bb;
        if (ACT == 1) val = fmaxf(val, 0.f);
        if (ACT == 2) val = 1.f/(1.f + expf(-val));
        if (ACT == 3) val = tanhf(val);
        int row = rowb + r;
        if constexpr (EPI == 1){
          float zz = ez[(size_t)row*ezs + col];
          out[(size_t)row*ostride + ooff + col] =
              (1.f - zz)*eold[(size_t)row*eos + col] + zz*val;
        } else if constexpr (EPI == 2){
          out[(size_t)col*HW + row] += val;
        } else {
          out[(size_t)row*ostride + ooff + col] = val;
        }
      }
    }
  }
}

extern "C" void kernel_launch(void* const* d_in, const int* in_sizes, int n_in,
                              void* d_out, int out_size, void* d_ws, size_t ws_size,
                              hipStream_t stream)
{
  (void)in_sizes; (void)n_in; (void)out_size; (void)ws_size;
  const float* f1s[3]    = {(const float*)d_in[0], (const float*)d_in[2], (const float*)d_in[4]};
  const float* f2s[3]    = {(const float*)d_in[1], (const float*)d_in[3], (const float*)d_in[5]};
  const float* net_in[3] = {(const float*)d_in[6], (const float*)d_in[8], (const float*)d_in[10]};
  const float* inp_in[3] = {(const float*)d_in[7], (const float*)d_in[9], (const float*)d_in[11]};
  const float* Wc1 = (const float*)d_in[12]; const float* bc1 = (const float*)d_in[13];
  const float* Wf1 = (const float*)d_in[14]; const float* bf1 = (const float*)d_in[15];
  const float* Wf2 = (const float*)d_in[16]; const float* bf2 = (const float*)d_in[17];
  const float* Wm  = (const float*)d_in[18]; const float* bm  = (const float*)d_in[19];
  const float* Wz  = (const float*)d_in[20]; const float* bz  = (const float*)d_in[21];
  const float* Wr  = (const float*)d_in[22]; const float* br  = (const float*)d_in[23];
  const float* Wq  = (const float*)d_in[24]; const float* bq  = (const float*)d_in[25];
  const float* Wh1 = (const float*)d_in[26]; const float* bh1 = (const float*)d_in[27];
  const float* Wh2 = (const float*)d_in[28]; const float* bh2 = (const float*)d_in[29];

  const int Hs[3] = {96, 48, 24};

  float* ws = (float*)d_ws;
  size_t off = 0;
  auto alloc = [&](size_t nfl)->float*{
    float* p = ws + off;
    off += (nfl + 3) & ~((size_t)3);
    return p;
  };

  float* f2l[3][4]; float* f1h[3]; float* netP[3][2]; float* hxb[3]; float* coords[3];
  for (int si = 0; si < 3; si++){
    int H = Hs[si], HW = H*H;
    for (int l = 0; l < 4; l++) f2l[si][l] = alloc((size_t)(HW >> (2*l))*128);
    f1h[si]     = alloc((size_t)HW*128);
    netP[si][0] = alloc((size_t)HW*96);
    netP[si][1] = alloc((size_t)HW*96);
    hxb[si]     = alloc((size_t)HW*256);
    coords[si]  = alloc((size_t)2*HW);
  }
  const int HWm = 96*96, MTm = HWm/16;
  float* corrfeat = alloc((size_t)HWm*224);
  float* flo1     = alloc((size_t)HWm*64);
  float* cmin     = alloc((size_t)HWm*128);
  float* zrb      = alloc((size_t)HWm*192);
  float* t128     = alloc((size_t)HWm*128);
  float* slotZ    = alloc((size_t)MTm*72*512);   // zr A (alive through q)
  float* slotX    = alloc((size_t)MTm*36*512);   // rotating
  float* Bc1 = alloc((size_t)7*8*512);
  float* Bf1 = alloc((size_t)4*4*512);
  float* Bf2 = alloc((size_t)18*4*512);
  float* Bm  = alloc((size_t)36*8*512);
  float* Bzr = alloc((size_t)72*12*512);
  float* Bq  = alloc((size_t)72*8*512);
  float* Bh1 = alloc((size_t)27*8*512);
  float* Bh2 = alloc((size_t)36*4*512);
  float* bzr = alloc(192);

  #define NB(n) dim3((unsigned)nblk((n), 256))

  // ---- one-time B packs ----
  k_packb<<<NB(7*8*64),  256,0,stream>>>(Wc1, Wc1, 96, 96, 196, 1, 7, 0, (short8*)Bc1, 8, 7);
  k_packb<<<NB(4*4*64),  256,0,stream>>>(Wf1, Wf1, 64, 64,  98, 1, 4, 1, (short8*)Bf1, 4, 4);
  k_packb<<<NB(18*4*64), 256,0,stream>>>(Wf2, Wf2, 32, 32,  64, 9, 2, 0, (short8*)Bf2, 4, 18);
  k_packb<<<NB(36*8*64), 256,0,stream>>>(Wm,  Wm,  80, 80, 128, 9, 4, 0, (short8*)Bm,  8, 36);
  k_packb<<<NB(72*12*64),256,0,stream>>>(Wz,  Wr,  96, 192,242, 9, 8, 0, (short8*)Bzr, 12, 72);
  k_packb<<<NB(72*8*64), 256,0,stream>>>(Wq,  Wq,  96, 96, 242, 9, 8, 0, (short8*)Bq,  8, 72);
  k_packb<<<NB(27*8*64), 256,0,stream>>>(Wh1, Wh1,128, 128, 96, 9, 3, 0, (short8*)Bh1, 8, 27);
  k_packb<<<NB(36*4*64), 256,0,stream>>>(Wh2, Wh2,  2,   2,128, 9, 4, 0, (short8*)Bh2, 4, 36);
  k_cat2<<<dim3(1), 256, 0, stream>>>(bz, br, bzr, 96);

  // ---- per-scale init ----
  for (int si = 0; si < 3; si++){
    int H = Hs[si], HW = H*H;
    k_trans_act<<<NB(96*HW), 256,0,stream>>>(net_in[si], netP[si][0], 96, 0, 96, HW, 0);
    k_trans_act<<<NB(64*HW), 256,0,stream>>>(inp_in[si], hxb[si], 256, 96, 64, HW, 1);
    k_zero_cols<<<NB(14*HW), 256,0,stream>>>(hxb[si], 256, 242, 14, HW);
    k_init_coords<<<NB(HW), 256,0,stream>>>(coords[si], H, H);
    k_transpose_hwc<<<NB(HW*128), 256,0,stream>>>(f2s[si], f2l[si][0], HW);
    k_transpose_hwc<<<NB(HW*128), 256,0,stream>>>(f1s[si], f1h[si], HW);
    for (int l = 1; l < 4; l++){
      int Hl = H >> l;
      k_pool_hwc<<<NB(Hl*Hl*128), 256,0,stream>>>(f2l[si][l-1], f2l[si][l], Hl, Hl);
    }
  }

  int cur[3] = {0, 0, 0};
  const int seq[6] = {2, 2, 1, 1, 0, 0};
  for (int it = 0; it < 6; it++){
    int si = seq[it];
    int H = Hs[si], W = H, HW = H*W;
    int MT = HW/16;
    float s = (si == 0) ? 2.0f : ((si == 1) ? 4.0f : 8.0f);
    float* netc = netP[si][cur[si]];
    float* netn = netP[si][cur[si]^1];
    float* co   = coords[si];
    float* hx   = hxb[si];
    unsigned gx = (unsigned)(MT/4);
    short8* AZ = (short8*)slotZ;
    short8* AX = (short8*)slotX;

    k_corr4<<<dim3((unsigned)(HW/4)), 256,0,stream>>>(
        f1h[si], f2l[si][0], f2l[si][1], f2l[si][2], f2l[si][3], co, corrfeat, H, W);
    k_hx_netflow<<<NB(98*HW), 256,0,stream>>>(hx, netc, co, H, W);

    // c1: corrfeat[224] -> cmin cols 0..95 (relu). KTN 7.
    k_packa<1,0><<<NB(MT*7*64), 256,0,stream>>>(corrfeat,224,0, nullptr,0,0, AX, H,W, 7, 7);
    k_gemm7<1,0,0><<<dim3(gx,2), 256,0,stream>>>(AX, AX, 7, 0, 7, (short8*)Bc1, 8, bc1,
        cmin, 128, 0, 96, HW, nullptr,0, nullptr,0);
    // f1: flow-from-coords 7x7 -> flo1[64] (relu). KTN 4.
    k_packa<1,2><<<NB(MT*4*64), 256,0,stream>>>(co,0,0, nullptr,0,0, AX, H,W, 4, 4);
    k_gemm7<1,0,0><<<dim3(gx,1), 256,0,stream>>>(AX, AX, 4, 0, 4, (short8*)Bf1, 4, bf1,
        flo1, 64, 0, 64, HW, nullptr,0, nullptr,0);
    // f2: flo1 -> cmin cols 96..127 (relu). KTN 18.
    k_packa<3,0><<<NB(MT*18*64), 256,0,stream>>>(flo1,64,0, nullptr,0,0, AX, H,W, 2, 18);
    k_gemm7<1,0,0><<<dim3(gx,1), 256,0,stream>>>(AX, AX, 18, 0, 2, (short8*)Bf2, 4, bf2,
        cmin, 128, 96, 32, HW, nullptr,0, nullptr,0);
    // m: cmin[128] -> hx cols 160..239 (relu). KTN 36.
    k_packa<3,0><<<NB(MT*36*64), 256,0,stream>>>(cmin,128,0, nullptr,0,0, AX, H,W, 4, 36);
    k_gemm7<1,0,0><<<dim3(gx,2), 256,0,stream>>>(AX, AX, 36, 0, 4, (short8*)Bm, 8, bm,
        hx, 256, 160, 80, HW, nullptr,0, nullptr,0);
    // zr: hx[256] -> zrb[192] (sigmoid). KTN 72.
    k_packa<3,0><<<NB(MT*72*64), 256,0,stream>>>(hx,256,0, nullptr,0,0, AZ, H,W, 8, 72);
    k_gemm7<2,0,0><<<dim3(gx,3), 256,0,stream>>>(AZ, AZ, 72, 0, 8, (short8*)Bzr, 12, bzr,
        zrb, 192, 0, 192, HW, nullptr,0, nullptr,0);
    // q replacement chunks: r*net (zrb cols 96.. * netc). KTN0 27.
    k_packa<3,1><<<NB(MT*27*64), 256,0,stream>>>(zrb,192,96, netc,96,0, AX, H,W, 3, 27);
    // q: tanh + GRU epilogue -> netn. A1=AZ (shared), A0=AX (replaced).
    k_gemm7<3,1,3><<<dim3(gx,2), 256,0,stream>>>(AZ, AX, 72, 27, 8, (short8*)Bq, 8, bq,
        netn, 96, 0, 96, HW, zrb, 192, netc, 96);
    // fh1: netn[96] -> t128 (relu). KTN 27.
    k_packa<3,0><<<NB(MT*27*64), 256,0,stream>>>(netn,96,0, nullptr,0,0, AX, H,W, 3, 27);
    k_gemm7<1,0,0><<<dim3(gx,2), 256,0,stream>>>(AX, AX, 27, 0, 3, (short8*)Bh1, 8, bh1,
        t128, 128, 0, 128, HW, nullptr,0, nullptr,0);
    // fh2: t128 -> coords (CHW +=). KTN 36.
    k_packa<3,0><<<NB(MT*36*64), 256,0,stream>>>(t128,128,0, nullptr,0,0, AX, H,W, 4, 36);
    k_gemm7<0,2,0><<<dim3(gx,1), 256,0,stream>>>(AX, AX, 36, 0, 4, (short8*)Bh2, 4, bh2,
        co, 0, 0, 2, HW, nullptr,0, nullptr,0);

    // prediction + coarse-to-fine handoff
    k_upflow<<<NB(2*192*192), 256,0,stream>>>(co, (float*)d_out + (size_t)it*2*192*192,
                                              H, W, 192, 192, s, 1);
    if (si > 0){
      int Hf = Hs[si-1];
      k_upflow<<<NB(2*Hf*Hf), 256,0,stream>>>(co, coords[si-1], H, W, Hf, Hf, 2.0f, 0);
    }
    cur[si] ^= 1;
  }
  #undef NB
}

// Round 8
// 1493.090 us; speedup vs baseline: 2.8373x; 1.0707x over previous
//
#include <hip/hip_runtime.h>
#include <hip/hip_bf16.h>
#include <math.h>

// ---------------------------------------------------------------------------
// RAFT-small forward — round 8: fused im2col GEMM (r6 idea, r7 parallelism).
// - k_fgemm: conv GEMM reading HWC fp32 directly; in-register hi/lo bf16
//   split, 3-term MFMA, NF=2 col-frags/wave, grid (MT/4, nt16/2).
//   Modes: plain HWC, flow-im2row (f1), r*net inline (q). Fused epilogues.
// - k_corr4: 4-way accumulator split (breaks 128-FMA serial chain) + fused
//   hx[net|flow] fill.
// - Launch-count cuts: fused upflow pair, fused per-scale init.
// ---------------------------------------------------------------------------

typedef __attribute__((ext_vector_type(8))) short short8;
typedef __attribute__((ext_vector_type(4))) float f32x4;

static inline int nblk(int n, int b){ return (n + b - 1) / b; }

__device__ __forceinline__ short bf16bits(float v){
  __hip_bfloat16 h = __float2bfloat16(v);
  return *reinterpret_cast<short*>(&h);
}
__device__ __forceinline__ float bf2f(short s){
  unsigned u = ((unsigned)(unsigned short)s) << 16;
  return *reinterpret_cast<float*>(&u);
}

// ---- init (per scale, fused): netP=tanh(net), hx[96..159]=relu(inp),
// hx[242..255]=0, coords grid. idx over HW*176.
__global__ void k_init_scale(const float* __restrict__ net_in, const float* __restrict__ inp_in,
                             float* __restrict__ netP, float* __restrict__ hx,
                             float* __restrict__ coords, int H, int W)
{
  int HW = H*W;
  int i = blockIdx.x*256 + threadIdx.x;
  if (i >= HW*176) return;
  int p = i / 176, c = i - p*176;
  if (c < 96){
    netP[(size_t)p*96 + c] = tanhf(net_in[(size_t)c*HW + p]);
  } else if (c < 160){
    hx[(size_t)p*256 + c] = fmaxf(inp_in[(size_t)(c-96)*HW + p], 0.f);
  } else if (c < 174){
    hx[(size_t)p*256 + 242 + (c-160)] = 0.f;
  } else if (c == 174){
    coords[p] = (float)(p % W);
  } else {
    coords[HW + p] = (float)(p / W);
  }
}
// fused transpose: f2 -> f2l0, f1 -> f1h
__global__ void k_transpose2(const float* __restrict__ f2, const float* __restrict__ f1,
                             float* __restrict__ f2h, float* __restrict__ f1h, int HW)
{
  int i = blockIdx.x*256 + threadIdx.x;
  int n = HW*128;
  if (i >= 2*n) return;
  if (i < n){ int p = i >> 7, c = i & 127; f2h[i] = f2[c*HW + p]; }
  else { int k = i - n; int p = k >> 7, c = k & 127; f1h[k] = f1[c*HW + p]; }
}
__global__ void k_pool_hwc(const float* __restrict__ in, float* __restrict__ out, int H2, int W2){
  int i = blockIdx.x*256 + threadIdx.x;
  int n = H2*W2*128;
  if (i >= n) return;
  int c = i & 127, p = i >> 7;
  int ox = p % W2, oy = p / W2;
  int W = 2*W2;
  const float* b = in + ((size_t)(2*oy)*W + 2*ox)*128 + c;
  out[i] = 0.25f*(b[0] + b[128] + b[(size_t)W*128] + b[(size_t)W*128 + 128]);
}
__global__ void k_cat2(const float* __restrict__ a, const float* __restrict__ b,
                       float* __restrict__ o, int n){
  int i = blockIdx.x*256 + threadIdx.x;
  if (i < 2*n) o[i] = (i < n) ? a[i] : b[i-n];
}

// ---- corr lookup + hx fill. 4 waves/block (1 query each). ----
__global__ __launch_bounds__(256)
void k_corr4(const float* __restrict__ f1h,
             const float* __restrict__ l0, const float* __restrict__ l1,
             const float* __restrict__ l2, const float* __restrict__ l3,
             const float* __restrict__ coords,
             float* __restrict__ out,           // [HW][224]
             float* __restrict__ hx,            // [HW][256]: cols 0..95=net, 240,241=flow
             const float* __restrict__ netc,    // [HW][96]
             int H, int W)
{
  int HW = H*W;
  int wv = threadIdx.x >> 6, lane = threadIdx.x & 63;
  int q = blockIdx.x*4 + wv;
  __shared__ __align__(16) float sf1[4][128];
  sf1[wv][lane]      = f1h[(size_t)q*128 + lane];
  sf1[wv][64 + lane] = f1h[(size_t)q*128 + 64 + lane];
  __syncthreads();
  float x = coords[q], y = coords[HW + q];
  const float* const lv[4] = {l0, l1, l2, l3};
  int u = lane & 7, v = lane >> 3;
  int t = lane;
  int j = min(t / 7, 6), k = min(t % 7, 6);
  const float4* a = (const float4*)&sf1[wv][0];
  #pragma unroll
  for (int i = 0; i < 4; i++){
    int Wi = W >> i, Hi = H >> i;
    float sc = 1.0f / (float)(1 << i);
    float xs = x*sc, ys = y*sc;
    float fx = floorf(xs), fy = floorf(ys);
    float wx = xs - fx, wy = ys - fy;
    float xf = fx + (float)(u - 3);
    float yf = fy + (float)(v - 3);
    float d = 0.0f;
    if (xf >= 0.0f && xf <= (float)(Wi-1) && yf >= 0.0f && yf <= (float)(Hi-1)){
      const float4* b = (const float4*)(lv[i] + ((size_t)((int)yf)*Wi + (int)xf)*128);
      float a0 = 0.f, a1 = 0.f, a2 = 0.f, a3 = 0.f;
      #pragma unroll
      for (int kk = 0; kk < 32; kk += 4){
        float4 av0 = a[kk],   bv0 = b[kk];
        float4 av1 = a[kk+1], bv1 = b[kk+1];
        float4 av2 = a[kk+2], bv2 = b[kk+2];
        float4 av3 = a[kk+3], bv3 = b[kk+3];
        a0 = fmaf(av0.x,bv0.x, fmaf(av0.y,bv0.y, fmaf(av0.z,bv0.z, fmaf(av0.w,bv0.w, a0))));
        a1 = fmaf(av1.x,bv1.x, fmaf(av1.y,bv1.y, fmaf(av1.z,bv1.z, fmaf(av1.w,bv1.w, a1))));
        a2 = fmaf(av2.x,bv2.x, fmaf(av2.y,bv2.y, fmaf(av2.z,bv2.z, fmaf(av2.w,bv2.w, a2))));
        a3 = fmaf(av3.x,bv3.x, fmaf(av3.y,bv3.y, fmaf(av3.z,bv3.z, fmaf(av3.w,bv3.w, a3))));
      }
      d = (a0 + a1) + (a2 + a3);
    }
    float d00 = __shfl(d,  k   *8 + j);
    float d10 = __shfl(d,  k   *8 + j + 1);
    float d01 = __shfl(d, (k+1)*8 + j);
    float d11 = __shfl(d, (k+1)*8 + j + 1);
    if (t < 49){
      float val = (1.f-wx)*(1.f-wy)*d00 + wx*(1.f-wy)*d10
                + (1.f-wx)*wy*d01 + wx*wy*d11;
      out[(size_t)q*224 + i*49 + t] = val * 0.08838834764831845f;
    }
  }
  if (lane < 28) out[(size_t)q*224 + 196 + lane] = 0.f;
  // hx fill: cols 0..95 = netc, 240/241 = flow
  { int c2 = lane, c3 = lane + 64;
    hx[(size_t)q*256 + c2] = netc[(size_t)q*96 + c2];
    if (c3 < 96) hx[(size_t)q*256 + c3] = netc[(size_t)q*96 + c3];
    else if (c3 == 96)  hx[(size_t)q*256 + 240] = x - (float)(q % W);
    else if (c3 == 97)  hx[(size_t)q*256 + 241] = y - (float)(q / W);
  }
}

// ---- combined upsampler: prediction (+optional coarse->fine handoff) ----
__global__ void k_upflow2(const float* __restrict__ cin, float* __restrict__ pred,
                          int Hin, int Win, float s,
                          float* __restrict__ conext, int Hf)
{
  int idx = blockIdx.x*256 + threadIdx.x;
  const int HWp = 192*192;
  int c, py, px, Hout, Wout;
  float n; int subtract; float* outp; size_t oidx;
  if (idx < 2*HWp){
    c = idx / HWp; int rem = idx - c*HWp; py = rem / 192; px = rem % 192;
    Hout = 192; Wout = 192; n = s; subtract = 1; outp = pred; oidx = idx;
  } else {
    int k2 = idx - 2*HWp;
    int HWf = Hf*Hf;
    if (Hf == 0 || k2 >= 2*HWf) return;
    c = k2 / HWf; int rem = k2 - c*HWf; py = rem / Hf; px = rem % Hf;
    Hout = Hf; Wout = Hf; n = 2.f; subtract = 0; outp = conext; oidx = k2;
  }
  float posy = (float)py * (float)(Hin-1) / (float)(Hout-1);
  float posx = (float)px * (float)(Win-1) / (float)(Wout-1);
  int iy = (int)floorf(posy); iy = max(0, min(iy, Hin-2));
  int ix = (int)floorf(posx); ix = max(0, min(ix, Win-2));
  float wy = posy - (float)iy, wx = posx - (float)ix;
  const float* base = cin + (size_t)c*Hin*Win;
  float s00 = 0.f, s10 = 0.f, s01 = 0.f, s11 = 0.f;
  if (subtract){
    if (c == 0){ s00 = (float)ix; s01 = (float)ix; s10 = (float)(ix+1); s11 = (float)(ix+1); }
    else       { s00 = (float)iy; s10 = (float)iy; s01 = (float)(iy+1); s11 = (float)(iy+1); }
  }
  float v00 = base[(size_t)iy*Win + ix]       - s00;
  float v10 = base[(size_t)iy*Win + ix + 1]   - s10;
  float v01 = base[(size_t)(iy+1)*Win + ix]   - s01;
  float v11 = base[(size_t)(iy+1)*Win + ix+1] - s11;
  float val = (1.f-wy)*((1.f-wx)*v00 + wx*v10) + wy*((1.f-wx)*v01 + wx*v11);
  outp[oidx] = n * val;
}

// ---- pack-B (weights -> frag order, k = tap*Cpad+ci, hi/lo). zr col-split;
// mode 1: f1 im2row weights. ----
__global__ void k_packb(const float* __restrict__ w0, const float* __restrict__ w1,
                        int split, int Cout, int Cin, int KT, int CH32, int mode,
                        short8* __restrict__ out, int nt16, int KTN)
{
  int gid = blockIdx.x*256 + threadIdx.x;
  if (gid >= KTN*nt16*64) return;
  int lane = gid & 63, blk = gid >> 6;
  int ct = blk % nt16, kt = blk / nt16;
  int col = ct*16 + (lane & 15);
  int tap = kt / CH32, chunk = kt - tap*CH32;
  int ci0 = chunk*32 + (lane >> 4)*8;
  short8 hi8, lo8;
  #pragma unroll
  for (int e = 0; e < 8; e++){
    int ci = ci0 + e;
    float v = 0.f;
    if (col < Cout && ci < Cin && tap < KT){
      if (mode == 1){
        v = w0[((size_t)col*2 + (ci & 1))*49 + (ci >> 1)];
      } else {
        const float* wp = (col < split) ? (w0 + (size_t)col*Cin*KT)
                                        : (w1 + (size_t)(col - split)*Cin*KT);
        v = wp[(size_t)ci*KT + tap];
      }
    }
    short h = bf16bits(v);
    hi8[e] = h;
    lo8[e] = bf16bits(v - bf2f(h));
  }
  out[(size_t)blk*128 + lane]      = hi8;
  out[(size_t)blk*128 + 64 + lane] = lo8;
}

// ---------------------------------------------------------------------------
// fused im2col GEMM. wave = 16 rows x 32 cols (NF=2), WG = 4 waves.
// grid (MT/4, ceil(nt16/2)). FM: 0 plain HWC; 2 flow-im2row (f1; in=coords CHW).
// NQ>0: chunks c<NQ read zr_[.,96+ci]*net_[.,ci] (q's r*net).
// ACT: 0none 1relu 2sig 3tanh. EPI: 0 store HWC; 1 GRU; 2 add CHW.
// ---------------------------------------------------------------------------
template<int KTW, int FM, int ACT, int EPI, int NQ>
__global__ __launch_bounds__(256)
void k_fgemm(const float* __restrict__ in, int sIn,
             const float* __restrict__ zr_, const float* __restrict__ net_,
             int CH32, int KTN,
             const short8* __restrict__ B, int nt16, const float* __restrict__ bias,
             float* __restrict__ out, int ostride, int ooff, int Cout,
             int H, int W,
             const float* __restrict__ ez, int ezs,
             const float* __restrict__ eold, int eos)
{
  const int P = KTW/2;
  int HW = H*W;
  int lane = threadIdx.x & 63;
  int mt = blockIdx.x*4 + (threadIdx.x >> 6);
  int ct0 = blockIdx.y*2;
  int p = mt*16 + (lane & 15);
  int x = p % W, y = p / W;
  int kq = (lane >> 4)*8;

  f32x4 acc0 = {0.f,0.f,0.f,0.f}, acc1 = acc0;

  int c = 0, tap = 0;
  int xx = x - P, yy = y - P;
  bool ok = ((unsigned)xx < (unsigned)W) && ((unsigned)yy < (unsigned)H);

  #pragma unroll 2
  for (int kt = 0; kt < KTN; kt++){
    float vv[8];
    if (FM == 2){
      #pragma unroll
      for (int e = 0; e < 8; e++){
        int ci = c*32 + kq + e;
        float v = 0.f;
        if (ci < 98){
          int t7 = ci >> 1, jj = ci & 1;
          int ddx = t7 % 7 - 3, ddy = t7 / 7 - 3;
          int x2 = x + ddx, y2 = y + ddy;
          if ((unsigned)x2 < (unsigned)W && (unsigned)y2 < (unsigned)H)
            v = in[(size_t)jj*HW + y2*W + x2] - (float)(jj ? y2 : x2);
        }
        vv[e] = v;
      }
    } else {
      if (ok){
        int base = yy*W + xx;
        if (NQ > 0 && c < NQ){
          const float4* zp = (const float4*)(zr_ + (size_t)base*192 + 96 + c*32 + kq);
          const float4* np = (const float4*)(net_ + (size_t)base*96 + c*32 + kq);
          float4 z0 = zp[0], z1 = zp[1], n0 = np[0], n1 = np[1];
          vv[0]=z0.x*n0.x; vv[1]=z0.y*n0.y; vv[2]=z0.z*n0.z; vv[3]=z0.w*n0.w;
          vv[4]=z1.x*n1.x; vv[5]=z1.y*n1.y; vv[6]=z1.z*n1.z; vv[7]=z1.w*n1.w;
        } else {
          const float4* ip = (const float4*)(in + (size_t)base*sIn + c*32 + kq);
          float4 a0 = ip[0], a1 = ip[1];
          vv[0]=a0.x; vv[1]=a0.y; vv[2]=a0.z; vv[3]=a0.w;
          vv[4]=a1.x; vv[5]=a1.y; vv[6]=a1.z; vv[7]=a1.w;
        }
      } else {
        #pragma unroll
        for (int e = 0; e < 8; e++) vv[e] = 0.f;
      }
    }
    short8 ah, al;
    #pragma unroll
    for (int e = 0; e < 8; e++){
      short h = bf16bits(vv[e]);
      ah[e] = h;
      al[e] = bf16bits(vv[e] - bf2f(h));
    }
    const short8* bp = B + ((size_t)kt*nt16 + ct0)*128 + lane;
    short8 bh0 = bp[0],   bl0 = bp[64];
    short8 bh1 = bp[128], bl1 = bp[192];
    acc0 = __builtin_amdgcn_mfma_f32_16x16x32_bf16(ah, bh0, acc0, 0, 0, 0);
    acc1 = __builtin_amdgcn_mfma_f32_16x16x32_bf16(ah, bh1, acc1, 0, 0, 0);
    acc0 = __builtin_amdgcn_mfma_f32_16x16x32_bf16(al, bh0, acc0, 0, 0, 0);
    acc1 = __builtin_amdgcn_mfma_f32_16x16x32_bf16(al, bh1, acc1, 0, 0, 0);
    acc0 = __builtin_amdgcn_mfma_f32_16x16x32_bf16(ah, bl0, acc0, 0, 0, 0);
    acc1 = __builtin_amdgcn_mfma_f32_16x16x32_bf16(ah, bl1, acc1, 0, 0, 0);
    if (++c == CH32){
      c = 0; tap++;
      int dx = tap % KTW - P, dy = tap / KTW - P;
      xx = x + dx; yy = y + dy;
      ok = ((unsigned)xx < (unsigned)W) && ((unsigned)yy < (unsigned)H);
    }
  }

  int rowb = mt*16 + ((lane >> 4) << 2);
  int colq = lane & 15;
  f32x4 av[2] = {acc0, acc1};
  #pragma unroll
  for (int f = 0; f < 2; f++){
    int col = (ct0 + f)*16 + colq;
    if (col < Cout){
      float bb = bias[col];
      #pragma unroll
      for (int r = 0; r < 4; r++){
        float val = av[f][r] + bb;
        if (ACT == 1) val = fmaxf(val, 0.f);
        if (ACT == 2) val = 1.f/(1.f + expf(-val));
        if (ACT == 3) val = tanhf(val);
        int row = rowb + r;
        if constexpr (EPI == 1){
          float zz = ez[(size_t)row*ezs + col];
          out[(size_t)row*ostride + ooff + col] =
              (1.f - zz)*eold[(size_t)row*eos + col] + zz*val;
        } else if constexpr (EPI == 2){
          out[(size_t)col*HW + row] += val;
        } else {
          out[(size_t)row*ostride + ooff + col] = val;
        }
      }
    }
  }
}

extern "C" void kernel_launch(void* const* d_in, const int* in_sizes, int n_in,
                              void* d_out, int out_size, void* d_ws, size_t ws_size,
                              hipStream_t stream)
{
  (void)in_sizes; (void)n_in; (void)out_size; (void)ws_size;
  const float* f1s[3]    = {(const float*)d_in[0], (const float*)d_in[2], (const float*)d_in[4]};
  const float* f2s[3]    = {(const float*)d_in[1], (const float*)d_in[3], (const float*)d_in[5]};
  const float* net_in[3] = {(const float*)d_in[6], (const float*)d_in[8], (const float*)d_in[10]};
  const float* inp_in[3] = {(const float*)d_in[7], (const float*)d_in[9], (const float*)d_in[11]};
  const float* Wc1 = (const float*)d_in[12]; const float* bc1 = (const float*)d_in[13];
  const float* Wf1 = (const float*)d_in[14]; const float* bf1 = (const float*)d_in[15];
  const float* Wf2 = (const float*)d_in[16]; const float* bf2 = (const float*)d_in[17];
  const float* Wm  = (const float*)d_in[18]; const float* bm  = (const float*)d_in[19];
  const float* Wz  = (const float*)d_in[20]; const float* bz  = (const float*)d_in[21];
  const float* Wr  = (const float*)d_in[22]; const float* br  = (const float*)d_in[23];
  const float* Wq  = (const float*)d_in[24]; const float* bq  = (const float*)d_in[25];
  const float* Wh1 = (const float*)d_in[26]; const float* bh1 = (const float*)d_in[27];
  const float* Wh2 = (const float*)d_in[28]; const float* bh2 = (const float*)d_in[29];

  const int Hs[3] = {96, 48, 24};

  float* ws = (float*)d_ws;
  size_t off = 0;
  auto alloc = [&](size_t nfl)->float*{
    float* p = ws + off;
    off += (nfl + 3) & ~((size_t)3);
    return p;
  };

  float* f2l[3][4]; float* f1h[3]; float* netP[3][2]; float* hxb[3]; float* coords[3];
  for (int si = 0; si < 3; si++){
    int H = Hs[si], HW = H*H;
    for (int l = 0; l < 4; l++) f2l[si][l] = alloc((size_t)(HW >> (2*l))*128);
    f1h[si]     = alloc((size_t)HW*128);
    netP[si][0] = alloc((size_t)HW*96);
    netP[si][1] = alloc((size_t)HW*96);
    hxb[si]     = alloc((size_t)HW*256);
    coords[si]  = alloc((size_t)2*HW);
  }
  const int HWm = 96*96;
  float* corrfeat = alloc((size_t)HWm*224);
  float* flo1     = alloc((size_t)HWm*64);
  float* cmin     = alloc((size_t)HWm*128);
  float* zrb      = alloc((size_t)HWm*192);
  float* t128     = alloc((size_t)HWm*128);
  float* Bc1 = alloc((size_t)7*6*512);
  float* Bf1 = alloc((size_t)4*4*512);
  float* Bf2 = alloc((size_t)18*2*512);
  float* Bm  = alloc((size_t)36*6*512);
  float* Bzr = alloc((size_t)72*12*512);
  float* Bq  = alloc((size_t)72*6*512);
  float* Bh1 = alloc((size_t)27*8*512);
  float* Bh2 = alloc((size_t)36*2*512);
  float* bzr = alloc(192);

  #define NB(n) dim3((unsigned)nblk((n), 256))

  // ---- one-time B packs ----
  k_packb<<<NB(7*6*64),  256,0,stream>>>(Wc1, Wc1, 96, 96, 196, 1, 7, 0, (short8*)Bc1, 6, 7);
  k_packb<<<NB(4*4*64),  256,0,stream>>>(Wf1, Wf1, 64, 64,  98, 1, 4, 1, (short8*)Bf1, 4, 4);
  k_packb<<<NB(18*2*64), 256,0,stream>>>(Wf2, Wf2, 32, 32,  64, 9, 2, 0, (short8*)Bf2, 2, 18);
  k_packb<<<NB(36*6*64), 256,0,stream>>>(Wm,  Wm,  80, 80, 128, 9, 4, 0, (short8*)Bm,  6, 36);
  k_packb<<<NB(72*12*64),256,0,stream>>>(Wz,  Wr,  96, 192,242, 9, 8, 0, (short8*)Bzr, 12, 72);
  k_packb<<<NB(72*6*64), 256,0,stream>>>(Wq,  Wq,  96, 96, 242, 9, 8, 0, (short8*)Bq,  6, 72);
  k_packb<<<NB(27*8*64), 256,0,stream>>>(Wh1, Wh1,128, 128, 96, 9, 3, 0, (short8*)Bh1, 8, 27);
  k_packb<<<NB(36*2*64), 256,0,stream>>>(Wh2, Wh2,  2,   2,128, 9, 4, 0, (short8*)Bh2, 2, 36);
  k_cat2<<<dim3(1), 256, 0, stream>>>(bz, br, bzr, 96);

  // ---- per-scale init ----
  for (int si = 0; si < 3; si++){
    int H = Hs[si], HW = H*H;
    k_init_scale<<<NB(HW*176), 256,0,stream>>>(net_in[si], inp_in[si], netP[si][0],
                                               hxb[si], coords[si], H, H);
    k_transpose2<<<NB(2*HW*128), 256,0,stream>>>(f2s[si], f1s[si], f2l[si][0], f1h[si], HW);
    for (int l = 1; l < 4; l++){
      int Hl = H >> l;
      k_pool_hwc<<<NB(Hl*Hl*128), 256,0,stream>>>(f2l[si][l-1], f2l[si][l], Hl, Hl);
    }
  }

  int cur[3] = {0, 0, 0};
  const int seq[6] = {2, 2, 1, 1, 0, 0};
  for (int it = 0; it < 6; it++){
    int si = seq[it];
    int H = Hs[si], W = H, HW = H*W;
    int MT = HW/16;
    float s = (si == 0) ? 2.0f : ((si == 1) ? 4.0f : 8.0f);
    float* netc = netP[si][cur[si]];
    float* netn = netP[si][cur[si]^1];
    float* co   = coords[si];
    float* hx   = hxb[si];
    unsigned gx = (unsigned)(MT/4);

    // corr + hx[net|flow] fill
    k_corr4<<<dim3((unsigned)(HW/4)), 256,0,stream>>>(
        f1h[si], f2l[si][0], f2l[si][1], f2l[si][2], f2l[si][3], co,
        corrfeat, hx, netc, H, W);

    // c1 (1x1, corr224 -> cmin[0..95], relu)
    k_fgemm<1,0,1,0,0><<<dim3(gx,3), 256,0,stream>>>(corrfeat,224, nullptr,nullptr, 7,7,
        (short8*)Bc1, 6, bc1, cmin, 128, 0, 96, H,W, nullptr,0, nullptr,0);
    // f1 (7x7 flow-im2row -> flo1[64], relu)
    k_fgemm<1,2,1,0,0><<<dim3(gx,2), 256,0,stream>>>(co,0, nullptr,nullptr, 4,4,
        (short8*)Bf1, 4, bf1, flo1, 64, 0, 64, H,W, nullptr,0, nullptr,0);
    // f2 (3x3, flo1 -> cmin[96..127], relu)
    k_fgemm<3,0,1,0,0><<<dim3(gx,1), 256,0,stream>>>(flo1,64, nullptr,nullptr, 2,18,
        (short8*)Bf2, 2, bf2, cmin, 128, 96, 32, H,W, nullptr,0, nullptr,0);
    // m (3x3, cmin128 -> hx[160..239], relu)
    k_fgemm<3,0,1,0,0><<<dim3(gx,3), 256,0,stream>>>(cmin,128, nullptr,nullptr, 4,36,
        (short8*)Bm, 6, bm, hx, 256, 160, 80, H,W, nullptr,0, nullptr,0);
    // zr (3x3, hx256 -> zrb[192], sigmoid)
    k_fgemm<3,0,2,0,0><<<dim3(gx,6), 256,0,stream>>>(hx,256, nullptr,nullptr, 8,72,
        (short8*)Bzr, 12, bzr, zrb, 192, 0, 192, H,W, nullptr,0, nullptr,0);
    // q (3x3, [r*net inline | hx tail] -> netn, tanh + GRU)
    k_fgemm<3,0,3,1,3><<<dim3(gx,3), 256,0,stream>>>(hx,256, zrb,netc, 8,72,
        (short8*)Bq, 6, bq, netn, 96, 0, 96, H,W, zrb,192, netc,96);
    // fh1 (3x3, netn96 -> t128, relu)
    k_fgemm<3,0,1,0,0><<<dim3(gx,4), 256,0,stream>>>(netn,96, nullptr,nullptr, 3,27,
        (short8*)Bh1, 8, bh1, t128, 128, 0, 128, H,W, nullptr,0, nullptr,0);
    // fh2 (3x3, t128 -> coords CHW +=)
    k_fgemm<3,0,0,2,0><<<dim3(gx,1), 256,0,stream>>>(t128,128, nullptr,nullptr, 4,36,
        (short8*)Bh2, 2, bh2, co, 0, 0, 2, H,W, nullptr,0, nullptr,0);

    // prediction + optional handoff (one launch)
    int Hf = (si > 0) ? Hs[si-1] : 0;
    float* conext = (si > 0) ? coords[si-1] : nullptr;
    k_upflow2<<<NB(2*192*192 + (Hf ? 2*Hf*Hf : 0)), 256,0,stream>>>(
        co, (float*)d_out + (size_t)it*2*192*192, H, W, s, conext, Hf);

    cur[si] ^= 1;
  }
  #undef NB
}

// Round 9
// 1487.458 us; speedup vs baseline: 2.8481x; 1.0038x over previous
//
#include <hip/hip_runtime.h>
#include <hip/hip_bf16.h>
#include <math.h>

// ---------------------------------------------------------------------------
// RAFT-small forward — round 9: stored hi/lo bf16 operand planes.
// r8 showed VALUBusy(16%) > MfmaUtil(8.7%): the in-GEMM hi/lo split was
// recomputed per col-pass and per tap. Now every GEMM-A buffer is stored as
// bf16 hi/lo planes [HW][2][Cpad], written once by producer epilogues
// (bit-identical numerics). GEMM inner loop = pure loads + MFMA. NF widened
// (zr 2->4) to cut redundant A passes. fp32 planes kept only where semantics
// need them (netP GRU-old, zrb, coords).
// ---------------------------------------------------------------------------

typedef __attribute__((ext_vector_type(8))) short short8;
typedef __attribute__((ext_vector_type(4))) float f32x4;

static inline int nblk(int n, int b){ return (n + b - 1) / b; }

__device__ __forceinline__ short bf16bits(float v){
  __hip_bfloat16 h = __float2bfloat16(v);
  return *reinterpret_cast<short*>(&h);
}
__device__ __forceinline__ float bf2f(short s){
  unsigned u = ((unsigned)(unsigned short)s) << 16;
  return *reinterpret_cast<float*>(&u);
}
__device__ __forceinline__ void split1(float v, unsigned short* hi, unsigned short* lo){
  short h = bf16bits(v);
  *hi = (unsigned short)h;
  *lo = (unsigned short)bf16bits(v - bf2f(h));
}

// ---- init (per scale): netP fp32+netS hi/lo = tanh(net); hxS[96..159]=relu(inp);
// hxS[242..255]=0; coords grid. idx over HW*176.
__global__ void k_init_scale(const float* __restrict__ net_in, const float* __restrict__ inp_in,
                             float* __restrict__ netP, unsigned short* __restrict__ netS,
                             unsigned short* __restrict__ hxS,
                             float* __restrict__ coords, int H, int W)
{
  int HW = H*W;
  int i = blockIdx.x*256 + threadIdx.x;
  if (i >= HW*176) return;
  int p = i / 176, c = i - p*176;
  if (c < 96){
    float t = tanhf(net_in[(size_t)c*HW + p]);
    netP[(size_t)p*96 + c] = t;
    split1(t, &netS[(size_t)p*192 + c], &netS[(size_t)p*192 + 96 + c]);
  } else if (c < 160){
    float r = fmaxf(inp_in[(size_t)(c-96)*HW + p], 0.f);
    split1(r, &hxS[(size_t)p*512 + c], &hxS[(size_t)p*512 + 256 + c]);
  } else if (c < 174){
    int col = 242 + (c - 160);
    hxS[(size_t)p*512 + col] = 0;
    hxS[(size_t)p*512 + 256 + col] = 0;
  } else if (c == 174){
    coords[p] = (float)(p % W);
  } else {
    coords[HW + p] = (float)(p / W);
  }
}
__global__ void k_transpose2(const float* __restrict__ f2, const float* __restrict__ f1,
                             float* __restrict__ f2h, float* __restrict__ f1h, int HW)
{
  int i = blockIdx.x*256 + threadIdx.x;
  int n = HW*128;
  if (i >= 2*n) return;
  if (i < n){ int p = i >> 7, c = i & 127; f2h[i] = f2[c*HW + p]; }
  else { int k = i - n; int p = k >> 7, c = k & 127; f1h[k] = f1[c*HW + p]; }
}
__global__ void k_pool_hwc(const float* __restrict__ in, float* __restrict__ out, int H2, int W2){
  int i = blockIdx.x*256 + threadIdx.x;
  int n = H2*W2*128;
  if (i >= n) return;
  int c = i & 127, p = i >> 7;
  int ox = p % W2, oy = p / W2;
  int W = 2*W2;
  const float* b = in + ((size_t)(2*oy)*W + 2*ox)*128 + c;
  out[i] = 0.25f*(b[0] + b[128] + b[(size_t)W*128] + b[(size_t)W*128 + 128]);
}
__global__ void k_cat2(const float* __restrict__ a, const float* __restrict__ b,
                       float* __restrict__ o, int n){
  int i = blockIdx.x*256 + threadIdx.x;
  if (i < 2*n) o[i] = (i < n) ? a[i] : b[i-n];
}

// ---- corr lookup + hx fill. 4 waves/block. corrS hi/lo out [HW][2][224]. ----
__global__ __launch_bounds__(256)
void k_corr4(const float* __restrict__ f1h,
             const float* __restrict__ l0, const float* __restrict__ l1,
             const float* __restrict__ l2, const float* __restrict__ l3,
             const float* __restrict__ coords,
             unsigned short* __restrict__ corrS,   // [HW][2][224]
             unsigned short* __restrict__ hxS,     // [HW][2][256]
             const unsigned short* __restrict__ netS, // [HW][2][96]
             int H, int W)
{
  int HW = H*W;
  int wv = threadIdx.x >> 6, lane = threadIdx.x & 63;
  int q = blockIdx.x*4 + wv;
  __shared__ __align__(16) float sf1[4][128];
  sf1[wv][lane]      = f1h[(size_t)q*128 + lane];
  sf1[wv][64 + lane] = f1h[(size_t)q*128 + 64 + lane];
  __syncthreads();
  float x = coords[q], y = coords[HW + q];
  const float* const lv[4] = {l0, l1, l2, l3};
  int u = lane & 7, v = lane >> 3;
  int t = lane;
  int j = min(t / 7, 6), k = min(t % 7, 6);
  const float4* a = (const float4*)&sf1[wv][0];
  #pragma unroll
  for (int i = 0; i < 4; i++){
    int Wi = W >> i, Hi = H >> i;
    float sc = 1.0f / (float)(1 << i);
    float xs = x*sc, ys = y*sc;
    float fx = floorf(xs), fy = floorf(ys);
    float wx = xs - fx, wy = ys - fy;
    float xf = fx + (float)(u - 3);
    float yf = fy + (float)(v - 3);
    float d = 0.0f;
    if (xf >= 0.0f && xf <= (float)(Wi-1) && yf >= 0.0f && yf <= (float)(Hi-1)){
      const float4* b = (const float4*)(lv[i] + ((size_t)((int)yf)*Wi + (int)xf)*128);
      float a0 = 0.f, a1 = 0.f, a2 = 0.f, a3 = 0.f;
      #pragma unroll
      for (int kk = 0; kk < 32; kk += 4){
        float4 av0 = a[kk],   bv0 = b[kk];
        float4 av1 = a[kk+1], bv1 = b[kk+1];
        float4 av2 = a[kk+2], bv2 = b[kk+2];
        float4 av3 = a[kk+3], bv3 = b[kk+3];
        a0 = fmaf(av0.x,bv0.x, fmaf(av0.y,bv0.y, fmaf(av0.z,bv0.z, fmaf(av0.w,bv0.w, a0))));
        a1 = fmaf(av1.x,bv1.x, fmaf(av1.y,bv1.y, fmaf(av1.z,bv1.z, fmaf(av1.w,bv1.w, a1))));
        a2 = fmaf(av2.x,bv2.x, fmaf(av2.y,bv2.y, fmaf(av2.z,bv2.z, fmaf(av2.w,bv2.w, a2))));
        a3 = fmaf(av3.x,bv3.x, fmaf(av3.y,bv3.y, fmaf(av3.z,bv3.z, fmaf(av3.w,bv3.w, a3))));
      }
      d = (a0 + a1) + (a2 + a3);
    }
    float d00 = __shfl(d,  k   *8 + j);
    float d10 = __shfl(d,  k   *8 + j + 1);
    float d01 = __shfl(d, (k+1)*8 + j);
    float d11 = __shfl(d, (k+1)*8 + j + 1);
    if (t < 49){
      float val = ((1.f-wx)*(1.f-wy)*d00 + wx*(1.f-wy)*d10
                + (1.f-wx)*wy*d01 + wx*wy*d11) * 0.08838834764831845f;
      split1(val, &corrS[(size_t)q*448 + i*49 + t], &corrS[(size_t)q*448 + 224 + i*49 + t]);
    }
  }
  if (lane < 28){
    corrS[(size_t)q*448 + 196 + lane] = 0;
    corrS[(size_t)q*448 + 224 + 196 + lane] = 0;
  }
  // hx fill: cols 0..95 from netS; flow 240/241 from coords
  hxS[(size_t)q*512 + lane]       = netS[(size_t)q*192 + lane];
  hxS[(size_t)q*512 + 256 + lane] = netS[(size_t)q*192 + 96 + lane];
  if (lane < 32){
    hxS[(size_t)q*512 + 64 + lane]       = netS[(size_t)q*192 + 64 + lane];
    hxS[(size_t)q*512 + 256 + 64 + lane] = netS[(size_t)q*192 + 96 + 64 + lane];
  } else if (lane == 32){
    split1(x - (float)(q % W), &hxS[(size_t)q*512 + 240], &hxS[(size_t)q*512 + 256 + 240]);
  } else if (lane == 33){
    split1(y - (float)(q / W), &hxS[(size_t)q*512 + 241], &hxS[(size_t)q*512 + 256 + 241]);
  }
}

// ---- combined upsampler ----
__global__ void k_upflow2(const float* __restrict__ cin, float* __restrict__ pred,
                          int Hin, int Win, float s,
                          float* __restrict__ conext, int Hf)
{
  int idx = blockIdx.x*256 + threadIdx.x;
  const int HWp = 192*192;
  int c, py, px, Hout, Wout;
  float n; int subtract; float* outp; size_t oidx;
  if (idx < 2*HWp){
    c = idx / HWp; int rem = idx - c*HWp; py = rem / 192; px = rem % 192;
    Hout = 192; Wout = 192; n = s; subtract = 1; outp = pred; oidx = idx;
  } else {
    int k2 = idx - 2*HWp;
    int HWf = Hf*Hf;
    if (Hf == 0 || k2 >= 2*HWf) return;
    c = k2 / HWf; int rem = k2 - c*HWf; py = rem / Hf; px = rem % Hf;
    Hout = Hf; Wout = Hf; n = 2.f; subtract = 0; outp = conext; oidx = k2;
  }
  float posy = (float)py * (float)(Hin-1) / (float)(Hout-1);
  float posx = (float)px * (float)(Win-1) / (float)(Wout-1);
  int iy = (int)floorf(posy); iy = max(0, min(iy, Hin-2));
  int ix = (int)floorf(posx); ix = max(0, min(ix, Win-2));
  float wy = posy - (float)iy, wx = posx - (float)ix;
  const float* base = cin + (size_t)c*Hin*Win;
  float s00 = 0.f, s10 = 0.f, s01 = 0.f, s11 = 0.f;
  if (subtract){
    if (c == 0){ s00 = (float)ix; s01 = (float)ix; s10 = (float)(ix+1); s11 = (float)(ix+1); }
    else       { s00 = (float)iy; s10 = (float)iy; s01 = (float)(iy+1); s11 = (float)(iy+1); }
  }
  float v00 = base[(size_t)iy*Win + ix]       - s00;
  float v10 = base[(size_t)iy*Win + ix + 1]   - s10;
  float v01 = base[(size_t)(iy+1)*Win + ix]   - s01;
  float v11 = base[(size_t)(iy+1)*Win + ix+1] - s11;
  float val = (1.f-wy)*((1.f-wx)*v00 + wx*v10) + wy*((1.f-wx)*v01 + wx*v11);
  outp[oidx] = n * val;
}

// ---- pack-B (unchanged layout) ----
__global__ void k_packb(const float* __restrict__ w0, const float* __restrict__ w1,
                        int split, int Cout, int Cin, int KT, int CH32, int mode,
                        short8* __restrict__ out, int nt16, int KTN)
{
  int gid = blockIdx.x*256 + threadIdx.x;
  if (gid >= KTN*nt16*64) return;
  int lane = gid & 63, blk = gid >> 6;
  int ct = blk % nt16, kt = blk / nt16;
  int col = ct*16 + (lane & 15);
  int tap = kt / CH32, chunk = kt - tap*CH32;
  int ci0 = chunk*32 + (lane >> 4)*8;
  short8 hi8, lo8;
  #pragma unroll
  for (int e = 0; e < 8; e++){
    int ci = ci0 + e;
    float v = 0.f;
    if (col < Cout && ci < Cin && tap < KT){
      if (mode == 1){
        v = w0[((size_t)col*2 + (ci & 1))*49 + (ci >> 1)];
      } else {
        const float* wp = (col < split) ? (w0 + (size_t)col*Cin*KT)
                                        : (w1 + (size_t)(col - split)*Cin*KT);
        v = wp[(size_t)ci*KT + tap];
      }
    }
    short h = bf16bits(v);
    hi8[e] = h;
    lo8[e] = bf16bits(v - bf2f(h));
  }
  out[(size_t)blk*128 + lane]      = hi8;
  out[(size_t)blk*128 + 64 + lane] = lo8;
}

// ---------------------------------------------------------------------------
// GEMM over stored hi/lo A planes. wave = 16 rows x NF*16 cols, WG = 4 waves.
// grid (MT/4, nt16/NF). FM: 0 A planes; 2 flow-im2row from coF (f1).
// NQ>0: chunks c<NQ compute r*net inline from zr_ (fp32) x net_ (fp32).
// ACT: 0none 1relu 2sig 3tanh.
// EPI: 0 store hi/lo planes; 1 GRU -> fp32 + hi/lo; 2 add CHW fp32; 3 fp32 only.
// ---------------------------------------------------------------------------
template<int KTW, int FM, int ACT, int EPI, int NQ, int NF>
__global__ __launch_bounds__(256)
void k_fgemm(const unsigned short* __restrict__ A, int Cpad,
             const float* __restrict__ zr_, const float* __restrict__ net_,
             const float* __restrict__ coF,
             int CH32, int KTN,
             const short8* __restrict__ B, int nt16, const float* __restrict__ bias,
             float* __restrict__ outF, int osF, int ooF,
             unsigned short* __restrict__ outS, int CpadS, int ooS,
             int Cout, int H, int W,
             const float* __restrict__ ez, int ezs,
             const float* __restrict__ eold, int eos)
{
  const int P = KTW/2;
  int HW = H*W;
  int lane = threadIdx.x & 63;
  int mt = blockIdx.x*4 + (threadIdx.x >> 6);
  int ct0 = blockIdx.y*NF;
  int p = mt*16 + (lane & 15);
  int x = p % W, y = p / W;
  int kq = (lane >> 4)*8;

  f32x4 acc[NF];
  #pragma unroll
  for (int f = 0; f < NF; f++) acc[f] = f32x4{0.f,0.f,0.f,0.f};

  int c = 0, tap = 0;
  int xx = x - P, yy = y - P;
  bool ok = ((unsigned)xx < (unsigned)W) && ((unsigned)yy < (unsigned)H);

  #pragma unroll 2
  for (int kt = 0; kt < KTN; kt++){
    short8 ah = short8{0,0,0,0,0,0,0,0}, al = ah;
    if (FM == 2){
      float vv[8];
      #pragma unroll
      for (int e = 0; e < 8; e++){
        int ci = c*32 + kq + e;
        float v = 0.f;
        if (ci < 98){
          int t7 = ci >> 1, jj = ci & 1;
          int ddx = t7 % 7 - 3, ddy = t7 / 7 - 3;
          int x2 = x + ddx, y2 = y + ddy;
          if ((unsigned)x2 < (unsigned)W && (unsigned)y2 < (unsigned)H)
            v = coF[(size_t)jj*HW + y2*W + x2] - (float)(jj ? y2 : x2);
        }
        vv[e] = v;
      }
      #pragma unroll
      for (int e = 0; e < 8; e++){
        short h = bf16bits(vv[e]);
        ah[e] = h;
        al[e] = bf16bits(vv[e] - bf2f(h));
      }
    } else if (ok){
      int base = yy*W + xx;
      if (NQ > 0 && c < NQ){
        const float4* zp = (const float4*)(zr_ + (size_t)base*192 + 96 + c*32 + kq);
        const float4* np = (const float4*)(net_ + (size_t)base*96 + c*32 + kq);
        float4 z0 = zp[0], z1 = zp[1], n0 = np[0], n1 = np[1];
        float vv[8] = {z0.x*n0.x, z0.y*n0.y, z0.z*n0.z, z0.w*n0.w,
                       z1.x*n1.x, z1.y*n1.y, z1.z*n1.z, z1.w*n1.w};
        #pragma unroll
        for (int e = 0; e < 8; e++){
          short h = bf16bits(vv[e]);
          ah[e] = h;
          al[e] = bf16bits(vv[e] - bf2f(h));
        }
      } else {
        const unsigned short* ap = A + (size_t)base*2*Cpad + c*32 + kq;
        ah = *(const short8*)ap;
        al = *(const short8*)(ap + Cpad);
      }
    }
    const short8* bp = B + ((size_t)kt*nt16 + ct0)*128 + lane;
    #pragma unroll
    for (int f = 0; f < NF; f++){
      short8 bh = bp[(size_t)f*128], bl = bp[(size_t)f*128 + 64];
      acc[f] = __builtin_amdgcn_mfma_f32_16x16x32_bf16(ah, bh, acc[f], 0, 0, 0);
      acc[f] = __builtin_amdgcn_mfma_f32_16x16x32_bf16(al, bh, acc[f], 0, 0, 0);
      acc[f] = __builtin_amdgcn_mfma_f32_16x16x32_bf16(ah, bl, acc[f], 0, 0, 0);
    }
    if (++c == CH32){
      c = 0; tap++;
      int dx = tap % KTW - P, dy = tap / KTW - P;
      xx = x + dx; yy = y + dy;
      ok = ((unsigned)xx < (unsigned)W) && ((unsigned)yy < (unsigned)H);
    }
  }

  int rowb = mt*16 + ((lane >> 4) << 2);
  int colq = lane & 15;
  #pragma unroll
  for (int f = 0; f < NF; f++){
    int col = (ct0 + f)*16 + colq;
    if (col < Cout){
      float bb = bias[col];
      #pragma unroll
      for (int r = 0; r < 4; r++){
        float val = acc[f][r] + bb;
        if (ACT == 1) val = fmaxf(val, 0.f);
        if (ACT == 2) val = 1.f/(1.f + expf(-val));
        if (ACT == 3) val = tanhf(val);
        int row = rowb + r;
        if constexpr (EPI == 2){
          outF[(size_t)col*HW + row] += val;
        } else {
          if constexpr (EPI == 1){
            float zz = ez[(size_t)row*ezs + col];
            val = (1.f - zz)*eold[(size_t)row*eos + col] + zz*val;
          }
          if constexpr (EPI == 1 || EPI == 3)
            outF[(size_t)row*osF + ooF + col] = val;
          if constexpr (EPI == 0 || EPI == 1)
            split1(val, &outS[(size_t)row*2*CpadS + ooS + col],
                        &outS[(size_t)row*2*CpadS + CpadS + ooS + col]);
        }
      }
    }
  }
}

extern "C" void kernel_launch(void* const* d_in, const int* in_sizes, int n_in,
                              void* d_out, int out_size, void* d_ws, size_t ws_size,
                              hipStream_t stream)
{
  (void)in_sizes; (void)n_in; (void)out_size; (void)ws_size;
  const float* f1s[3]    = {(const float*)d_in[0], (const float*)d_in[2], (const float*)d_in[4]};
  const float* f2s[3]    = {(const float*)d_in[1], (const float*)d_in[3], (const float*)d_in[5]};
  const float* net_in[3] = {(const float*)d_in[6], (const float*)d_in[8], (const float*)d_in[10]};
  const float* inp_in[3] = {(const float*)d_in[7], (const float*)d_in[9], (const float*)d_in[11]};
  const float* Wc1 = (const float*)d_in[12]; const float* bc1 = (const float*)d_in[13];
  const float* Wf1 = (const float*)d_in[14]; const float* bf1 = (const float*)d_in[15];
  const float* Wf2 = (const float*)d_in[16]; const float* bf2 = (const float*)d_in[17];
  const float* Wm  = (const float*)d_in[18]; const float* bm  = (const float*)d_in[19];
  const float* Wz  = (const float*)d_in[20]; const float* bz  = (const float*)d_in[21];
  const float* Wr  = (const float*)d_in[22]; const float* br  = (const float*)d_in[23];
  const float* Wq  = (const float*)d_in[24]; const float* bq  = (const float*)d_in[25];
  const float* Wh1 = (const float*)d_in[26]; const float* bh1 = (const float*)d_in[27];
  const float* Wh2 = (const float*)d_in[28]; const float* bh2 = (const float*)d_in[29];

  const int Hs[3] = {96, 48, 24};

  float* ws = (float*)d_ws;
  size_t off = 0;
  auto alloc = [&](size_t nfl)->float*{
    float* p = ws + off;
    off += (nfl + 3) & ~((size_t)3);
    return p;
  };

  float* f2l[3][4]; float* f1h[3]; float* netP[3][2]; float* coords[3];
  unsigned short* netS[3][2]; unsigned short* hxS[3];
  for (int si = 0; si < 3; si++){
    int H = Hs[si], HW = H*H;
    for (int l = 0; l < 4; l++) f2l[si][l] = alloc((size_t)(HW >> (2*l))*128);
    f1h[si]     = alloc((size_t)HW*128);
    netP[si][0] = alloc((size_t)HW*96);
    netP[si][1] = alloc((size_t)HW*96);
    netS[si][0] = (unsigned short*)alloc((size_t)HW*96);
    netS[si][1] = (unsigned short*)alloc((size_t)HW*96);
    hxS[si]     = (unsigned short*)alloc((size_t)HW*256);
    coords[si]  = alloc((size_t)2*HW);
  }
  const int HWm = 96*96;
  unsigned short* corrS = (unsigned short*)alloc((size_t)HWm*224);
  unsigned short* flo1S = (unsigned short*)alloc((size_t)HWm*64);
  unsigned short* cminS = (unsigned short*)alloc((size_t)HWm*128);
  unsigned short* t128S = (unsigned short*)alloc((size_t)HWm*128);
  float* zrb = alloc((size_t)HWm*192);
  float* Bc1 = alloc((size_t)7*6*512);
  float* Bf1 = alloc((size_t)4*4*512);
  float* Bf2 = alloc((size_t)18*2*512);
  float* Bm  = alloc((size_t)36*6*512);
  float* Bzr = alloc((size_t)72*12*512);
  float* Bq  = alloc((size_t)72*6*512);
  float* Bh1 = alloc((size_t)27*8*512);
  float* Bh2 = alloc((size_t)36*2*512);
  float* bzr = alloc(192);

  #define NB(n) dim3((unsigned)nblk((n), 256))

  // ---- one-time B packs ----
  k_packb<<<NB(7*6*64),  256,0,stream>>>(Wc1, Wc1, 96, 96, 196, 1, 7, 0, (short8*)Bc1, 6, 7);
  k_packb<<<NB(4*4*64),  256,0,stream>>>(Wf1, Wf1, 64, 64,  98, 1, 4, 1, (short8*)Bf1, 4, 4);
  k_packb<<<NB(18*2*64), 256,0,stream>>>(Wf2, Wf2, 32, 32,  64, 9, 2, 0, (short8*)Bf2, 2, 18);
  k_packb<<<NB(36*6*64), 256,0,stream>>>(Wm,  Wm,  80, 80, 128, 9, 4, 0, (short8*)Bm,  6, 36);
  k_packb<<<NB(72*12*64),256,0,stream>>>(Wz,  Wr,  96, 192,242, 9, 8, 0, (short8*)Bzr, 12, 72);
  k_packb<<<NB(72*6*64), 256,0,stream>>>(Wq,  Wq,  96, 96, 242, 9, 8, 0, (short8*)Bq,  6, 72);
  k_packb<<<NB(27*8*64), 256,0,stream>>>(Wh1, Wh1,128, 128, 96, 9, 3, 0, (short8*)Bh1, 8, 27);
  k_packb<<<NB(36*2*64), 256,0,stream>>>(Wh2, Wh2,  2,   2,128, 9, 4, 0, (short8*)Bh2, 2, 36);
  k_cat2<<<dim3(1), 256, 0, stream>>>(bz, br, bzr, 96);

  // ---- per-scale init ----
  for (int si = 0; si < 3; si++){
    int H = Hs[si], HW = H*H;
    k_init_scale<<<NB(HW*176), 256,0,stream>>>(net_in[si], inp_in[si], netP[si][0],
                                               netS[si][0], hxS[si], coords[si], H, H);
    k_transpose2<<<NB(2*HW*128), 256,0,stream>>>(f2s[si], f1s[si], f2l[si][0], f1h[si], HW);
    for (int l = 1; l < 4; l++){
      int Hl = H >> l;
      k_pool_hwc<<<NB(Hl*Hl*128), 256,0,stream>>>(f2l[si][l-1], f2l[si][l], Hl, Hl);
    }
  }

  int cur[3] = {0, 0, 0};
  const int seq[6] = {2, 2, 1, 1, 0, 0};
  for (int it = 0; it < 6; it++){
    int si = seq[it];
    int H = Hs[si], W = H, HW = H*W;
    int MT = HW/16;
    float s = (si == 0) ? 2.0f : ((si == 1) ? 4.0f : 8.0f);
    float* netcF = netP[si][cur[si]];
    float* netnF = netP[si][cur[si]^1];
    unsigned short* netcS = netS[si][cur[si]];
    unsigned short* netnS = netS[si][cur[si]^1];
    float* co = coords[si];
    unsigned short* hx = hxS[si];
    unsigned gx = (unsigned)(MT/4);

    // corr (writes corrS hi/lo) + hx net/flow fill
    k_corr4<<<dim3((unsigned)(HW/4)), 256,0,stream>>>(
        f1h[si], f2l[si][0], f2l[si][1], f2l[si][2], f2l[si][3], co,
        corrS, hx, netcS, H, W);

    // c1 (1x1, corrS224 -> cminS[0..95], relu)  NF=3
    k_fgemm<1,0,1,0,0,3><<<dim3(gx,2), 256,0,stream>>>(corrS,224, nullptr,nullptr,nullptr, 7,7,
        (short8*)Bc1, 6, bc1, nullptr,0,0, cminS,128,0, 96, H,W, nullptr,0, nullptr,0);
    // f1 (7x7 flow-im2row -> flo1S, relu)  NF=2
    k_fgemm<1,2,1,0,0,2><<<dim3(gx,2), 256,0,stream>>>(nullptr,0, nullptr,nullptr,co, 4,4,
        (short8*)Bf1, 4, bf1, nullptr,0,0, flo1S,64,0, 64, H,W, nullptr,0, nullptr,0);
    // f2 (3x3, flo1S -> cminS[96..127], relu)  NF=2
    k_fgemm<3,0,1,0,0,2><<<dim3(gx,1), 256,0,stream>>>(flo1S,64, nullptr,nullptr,nullptr, 2,18,
        (short8*)Bf2, 2, bf2, nullptr,0,0, cminS,128,96, 32, H,W, nullptr,0, nullptr,0);
    // m (3x3, cminS -> hxS[160..239], relu)  NF=3
    k_fgemm<3,0,1,0,0,3><<<dim3(gx,2), 256,0,stream>>>(cminS,128, nullptr,nullptr,nullptr, 4,36,
        (short8*)Bm, 6, bm, nullptr,0,0, hx,256,160, 80, H,W, nullptr,0, nullptr,0);
    // zr (3x3, hxS -> zrb fp32, sigmoid)  NF=4
    k_fgemm<3,0,2,3,0,4><<<dim3(gx,3), 256,0,stream>>>(hx,256, nullptr,nullptr,nullptr, 8,72,
        (short8*)Bzr, 12, bzr, zrb,192,0, nullptr,0,0, 192, H,W, nullptr,0, nullptr,0);
    // q (3x3, [r*net inline | hxS tail] -> GRU -> netn fp32 + hi/lo)  NF=3
    k_fgemm<3,0,3,1,3,3><<<dim3(gx,2), 256,0,stream>>>(hx,256, zrb,netcF,nullptr, 8,72,
        (short8*)Bq, 6, bq, netnF,96,0, netnS,96,0, 96, H,W, zrb,192, netcF,96);
    // fh1 (3x3, netnS -> t128S, relu)  NF=4
    k_fgemm<3,0,1,0,0,4><<<dim3(gx,2), 256,0,stream>>>(netnS,96, nullptr,nullptr,nullptr, 3,27,
        (short8*)Bh1, 8, bh1, nullptr,0,0, t128S,128,0, 128, H,W, nullptr,0, nullptr,0);
    // fh2 (3x3, t128S -> coords CHW +=)  NF=2
    k_fgemm<3,0,0,2,0,2><<<dim3(gx,1), 256,0,stream>>>(t128S,128, nullptr,nullptr,nullptr, 4,36,
        (short8*)Bh2, 2, bh2, co,0,0, nullptr,0,0, 2, H,W, nullptr,0, nullptr,0);

    // prediction + optional handoff
    int Hf = (si > 0) ? Hs[si-1] : 0;
    float* conext = (si > 0) ? coords[si-1] : nullptr;
    k_upflow2<<<NB(2*192*192 + (Hf ? 2*Hf*Hf : 0)), 256,0,stream>>>(
        co, (float*)d_out + (size_t)it*2*192*192, H, W, s, conext, Hf);

    cur[si] ^= 1;
  }
  #undef NB
}